// Round 1
// baseline (807.851 us; speedup 1.0000x reference)
//
#include <hip/hip_runtime.h>
#include <stdint.h>

#define B_    4
#define A_    9
#define H_    50
#define W_    76
#define N_    (H_ * W_ * A_)   // 34200
#define PRE_  6000
#define POST_ 300
#define SORTN 8192

// generate_anchors(16) precomputed (exact, verified against the numpy code)
__constant__ float c_anchors[9][4] = {
    { -84.f,  -40.f,  99.f,  55.f},
    {-176.f,  -88.f, 191.f, 103.f},
    {-360.f, -184.f, 375.f, 199.f},
    { -56.f,  -56.f,  71.f,  71.f},
    {-120.f, -120.f, 135.f, 135.f},
    {-248.f, -248.f, 263.f, 263.f},
    { -36.f,  -80.f,  51.f,  95.f},
    { -80.f, -168.f,  95.f, 183.f},
    {-168.f, -344.f, 183.f, 359.f},
};

// ---- kernel 1: composite keys (~score_bits)<<32 | n  (ascending == score desc, idx asc)
__global__ void k_keys(const float* __restrict__ scores,
                       unsigned long long* __restrict__ keys) {
    int idx = blockIdx.x * 256 + threadIdx.x;
    const int total = B_ * A_ * H_ * W_;
    if (idx >= total) return;
    int w = idx % W_;
    int h = (idx / W_) % H_;
    int a = (idx / (W_ * H_)) % A_;
    int b = idx / (W_ * H_ * A_);
    float s = scores[(((b * 2 * A_) + A_ + a) * H_ + h) * W_ + w];
    unsigned int sb = __float_as_uint(s);          // s >= 0 -> monotone bits
    unsigned int n  = (unsigned int)((h * W_ + w) * A_ + a);
    keys[b * N_ + n] = (((unsigned long long)(~sb)) << 32) | (unsigned long long)n;
}

// ---- kernel 2: per-image radix-select of the rank-(PRE_-1) key (keys are distinct)
__global__ void k_select(const unsigned long long* __restrict__ keys,
                         unsigned long long* __restrict__ Tkey) {
    int b = blockIdx.x, tid = threadIdx.x;
    const unsigned long long* kk = keys + b * N_;
    __shared__ unsigned int hist[256];
    __shared__ unsigned long long s_pref;
    __shared__ int s_rem;
    if (tid == 0) { s_pref = 0ull; s_rem = PRE_ - 1; }
    __syncthreads();
    for (int pass = 0; pass < 8; ++pass) {
        int shift = 56 - 8 * pass;
        hist[tid] = 0;
        __syncthreads();
        unsigned long long pref = s_pref;
        for (int i = tid; i < N_; i += 256) {
            unsigned long long key = kk[i];
            if (pass == 0 || (key >> (shift + 8)) == pref)
                atomicAdd(&hist[(unsigned int)((key >> shift) & 255ull)], 1u);
        }
        __syncthreads();
        if (tid == 0) {
            int cum = 0, bin = 0;
            for (; bin < 256; ++bin) {
                int c = (int)hist[bin];
                if (cum + c > s_rem) break;
                cum += c;
            }
            s_rem -= cum;
            s_pref = (pref << 8) | (unsigned long long)bin;
        }
        __syncthreads();
    }
    if (tid == 0) Tkey[b] = s_pref;
}

// ---- kernel 3: compact the exactly-PRE_ keys <= threshold (unordered; sorted next)
__global__ void k_compact(const unsigned long long* __restrict__ keys,
                          const unsigned long long* __restrict__ Tkey,
                          unsigned long long* __restrict__ cand,
                          unsigned int* __restrict__ cnt) {
    int idx = blockIdx.x * 256 + threadIdx.x;
    if (idx >= B_ * N_) return;
    int b = idx / N_;
    unsigned long long key = keys[idx];
    if (key <= Tkey[b]) {
        unsigned int pos = atomicAdd(&cnt[b], 1u);
        if (pos < PRE_) cand[b * PRE_ + pos] = key;
    }
}

// box decode exactly in the reference op order; no FMA contraction
__device__ __forceinline__ void compute_box(int b, unsigned int n,
                                            const float* __restrict__ deltas,
                                            const float* __restrict__ im_info,
                                            float box[4]) {
#pragma clang fp contract(off)
    int a   = (int)(n % A_);
    int pos = (int)(n / A_);
    int w   = pos % W_;
    int h   = pos / W_;
    float a0 = c_anchors[a][0] + (float)(w * 16);
    float a1 = c_anchors[a][1] + (float)(h * 16);
    float a2 = c_anchors[a][2] + (float)(w * 16);
    float a3 = c_anchors[a][3] + (float)(h * 16);
    float wa  = a2 - a0 + 1.f;
    float ha  = a3 - a1 + 1.f;
    float cxa = a0 + 0.5f * wa;
    float cya = a1 + 0.5f * ha;
    int base = ((b * 4 * A_ + a * 4) * H_ + h) * W_ + w;
    const int chs = H_ * W_;
    float dx = deltas[base];
    float dy = deltas[base + chs];
    float dw = deltas[base + 2 * chs];
    float dh = deltas[base + 3 * chs];
    float pcx = dx * wa + cxa;
    float pcy = dy * ha + cya;
    float pw  = expf(dw) * wa;
    float ph  = expf(dh) * ha;
    float x1 = pcx - 0.5f * pw;
    float y1 = pcy - 0.5f * ph;
    float x2 = pcx + 0.5f * pw;
    float y2 = pcy + 0.5f * ph;
    float imh = im_info[b * 3 + 0], imw = im_info[b * 3 + 1];
    x1 = fminf(fmaxf(x1, 0.f), imw - 1.f);
    x2 = fminf(fmaxf(x2, 0.f), imw - 1.f);
    y1 = fminf(fmaxf(y1, 0.f), imh - 1.f);
    y2 = fminf(fmaxf(y2, 0.f), imh - 1.f);
    box[0] = x1; box[1] = y1; box[2] = x2; box[3] = y2;
}

// ---- kernel 4: per-image bitonic sort of 8192 keys in LDS, then gather+decode boxes
__global__ __launch_bounds__(1024) void k_sort(const unsigned long long* __restrict__ cand,
                                               const float* __restrict__ deltas,
                                               const float* __restrict__ im_info,
                                               float* __restrict__ sboxes) {
    int b = blockIdx.x, tid = threadIdx.x;
    __shared__ unsigned long long sk[SORTN];   // 64 KB
    for (int i = tid; i < SORTN; i += 1024)
        sk[i] = (i < PRE_) ? cand[b * PRE_ + i] : ~0ull;
    __syncthreads();
    for (int k = 2; k <= SORTN; k <<= 1) {
        for (int j = k >> 1; j > 0; j >>= 1) {
            for (int i = tid; i < SORTN; i += 1024) {
                int ixj = i ^ j;
                if (ixj > i) {
                    unsigned long long x = sk[i], y = sk[ixj];
                    bool up = ((i & k) == 0);
                    if ((x > y) == up) { sk[i] = y; sk[ixj] = x; }
                }
            }
            __syncthreads();
        }
    }
    float4* sb4 = (float4*)sboxes;
    for (int i = tid; i < PRE_; i += 1024) {
        unsigned int n = (unsigned int)(sk[i] & 0xffffffffull);
        float box[4];
        compute_box(b, n, deltas, im_info, box);
        sb4[b * PRE_ + i] = make_float4(box[0], box[1], box[2], box[3]);
    }
}

// ---- kernel 5: exact greedy NMS, 1 wave per image, early-exit at 300 kept
__global__ __launch_bounds__(64) void k_nms(const float* __restrict__ sboxes,
                                            float* __restrict__ out) {
    int b = blockIdx.x, lane = threadIdx.x;
    __shared__ float kx1[POST_ + 64], ky1[POST_ + 64], kx2[POST_ + 64],
                     ky2[POST_ + 64], kar[POST_ + 64];
    const float4* bb = (const float4*)sboxes + b * PRE_;
    float* ob = out + b * POST_ * 5;
    int kept = 0;
    for (int blk = 0; blk < PRE_ && kept < POST_; blk += 64) {
        int idx = blk + lane;
        bool valid = idx < PRE_;
        float x1 = 0.f, y1 = 0.f, x2 = 0.f, y2 = 0.f;
        if (valid) { float4 v = bb[idx]; x1 = v.x; y1 = v.y; x2 = v.z; y2 = v.w; }
        float area = ((x2 - x1) + 1.f) * ((y2 - y1) + 1.f);
        bool sup = !valid;
        // suppression vs global kept list
        for (int kk = 0; kk < kept; ++kk) {
            float iw = fminf(x2, kx2[kk]) - fmaxf(x1, kx1[kk]) + 1.f;
            float ih = fminf(y2, ky2[kk]) - fmaxf(y1, ky1[kk]) + 1.f;
            iw = fmaxf(iw, 0.f); ih = fmaxf(ih, 0.f);
            float inter = iw * ih;
            float iou = inter / ((area + kar[kk]) - inter);
            sup = sup | (iou > 0.7f);
            if (((kk & 15) == 15) && __ballot(!sup) == 0ull) break;
        }
        // intra-block exact greedy via mask arithmetic
        unsigned long long alive = __ballot(!sup);
        unsigned long long keepm = 0ull;
        while (alive) {
            int i = __builtin_ctzll(alive);
            keepm |= (1ull << i);
            alive &= ~(1ull << i);
            float ix1 = __shfl(x1, i), iy1 = __shfl(y1, i);
            float ix2 = __shfl(x2, i), iy2 = __shfl(y2, i);
            float iar = __shfl(area, i);
            float iw = fminf(x2, ix2) - fmaxf(x1, ix1) + 1.f;
            float ih = fminf(y2, iy2) - fmaxf(y1, iy1) + 1.f;
            iw = fmaxf(iw, 0.f); ih = fmaxf(ih, 0.f);
            float inter = iw * ih;
            float iou = inter / ((area + iar) - inter);
            alive &= ~__ballot((lane > i) && (iou > 0.7f));
        }
        if ((keepm >> lane) & 1ull) {
            int my = kept + __builtin_popcountll(keepm & ((1ull << lane) - 1ull));
            kx1[my] = x1; ky1[my] = y1; kx2[my] = x2; ky2[my] = y2; kar[my] = area;
            if (my < POST_) {
                ob[my * 5 + 0] = (float)b;
                ob[my * 5 + 1] = x1; ob[my * 5 + 2] = y1;
                ob[my * 5 + 3] = x2; ob[my * 5 + 4] = y2;
            }
        }
        kept += __builtin_popcountll(keepm);
        __syncthreads();
    }
    int start = kept < POST_ ? kept : POST_;
    for (int r = start + lane; r < POST_; r += 64) {
        ob[r * 5 + 0] = (float)b;
        ob[r * 5 + 1] = 0.f; ob[r * 5 + 2] = 0.f;
        ob[r * 5 + 3] = 0.f; ob[r * 5 + 4] = 0.f;
    }
}

extern "C" void kernel_launch(void* const* d_in, const int* in_sizes, int n_in,
                              void* d_out, int out_size, void* d_ws, size_t ws_size,
                              hipStream_t stream) {
    const float* scores  = (const float*)d_in[0];
    const float* deltas  = (const float*)d_in[1];
    const float* im_info = (const float*)d_in[2];
    float* out = (float*)d_out;

    // workspace layout
    char* ws = (char*)d_ws;
    unsigned long long* keys = (unsigned long long*)(ws);                  // B*N*8      = 1,094,400
    unsigned long long* cand = (unsigned long long*)(ws + 1094400);        // B*PRE*8    =   192,000
    unsigned long long* Tkey = (unsigned long long*)(ws + 1286400);        // B*8        =        32
    unsigned int*       cnt  = (unsigned int*)      (ws + 1286432);        // B*4        =        16
    float*              sbx  = (float*)             (ws + 1286448);        // B*PRE*4*4  =   384,000

    hipMemsetAsync(cnt, 0, B_ * sizeof(unsigned int), stream);

    const int total = B_ * A_ * H_ * W_;
    k_keys<<<(total + 255) / 256, 256, 0, stream>>>(scores, keys);
    k_select<<<B_, 256, 0, stream>>>(keys, Tkey);
    k_compact<<<(B_ * N_ + 255) / 256, 256, 0, stream>>>(keys, Tkey, cand, cnt);
    k_sort<<<B_, 1024, 0, stream>>>(cand, deltas, im_info, sbx);
    k_nms<<<B_, 64, 0, stream>>>(sbx, out);
}

// Round 2
// 561.158 us; speedup vs baseline: 1.4396x; 1.4396x over previous
//
#include <hip/hip_runtime.h>
#include <stdint.h>

#define B_    4
#define A_    9
#define H_    50
#define W_    76
#define N_    (H_ * W_ * A_)   // 34200
#define PRE_  6000
#define POST_ 300
#define SORTN 8192

// generate_anchors(16) precomputed (exact, verified against the numpy code)
__constant__ float c_anchors[9][4] = {
    { -84.f,  -40.f,  99.f,  55.f},
    {-176.f,  -88.f, 191.f, 103.f},
    {-360.f, -184.f, 375.f, 199.f},
    { -56.f,  -56.f,  71.f,  71.f},
    {-120.f, -120.f, 135.f, 135.f},
    {-248.f, -248.f, 263.f, 263.f},
    { -36.f,  -80.f,  51.f,  95.f},
    { -80.f, -168.f,  95.f, 183.f},
    {-168.f, -344.f, 183.f, 359.f},
};

// ---- kernel 1: composite keys (~score_bits)<<32 | n  (ascending == score desc, idx asc)
__global__ void k_keys(const float* __restrict__ scores,
                       unsigned long long* __restrict__ keys) {
    int idx = blockIdx.x * 256 + threadIdx.x;
    const int total = B_ * A_ * H_ * W_;
    if (idx >= total) return;
    int w = idx % W_;
    int h = (idx / W_) % H_;
    int a = (idx / (W_ * H_)) % A_;
    int b = idx / (W_ * H_ * A_);
    float s = scores[(((b * 2 * A_) + A_ + a) * H_ + h) * W_ + w];
    unsigned int sb = __float_as_uint(s);          // s >= 0 -> monotone bits
    unsigned int n  = (unsigned int)((h * W_ + w) * A_ + a);
    keys[b * N_ + n] = (((unsigned long long)(~sb)) << 32) | (unsigned long long)n;
}

// ---- kernel 2: per-image radix-select of the rank-(PRE_-1) key (keys are distinct)
__global__ void k_select(const unsigned long long* __restrict__ keys,
                         unsigned long long* __restrict__ Tkey) {
    int b = blockIdx.x, tid = threadIdx.x;
    const unsigned long long* kk = keys + b * N_;
    __shared__ unsigned int hist[256];
    __shared__ unsigned long long s_pref;
    __shared__ int s_rem;
    if (tid == 0) { s_pref = 0ull; s_rem = PRE_ - 1; }
    __syncthreads();
    for (int pass = 0; pass < 8; ++pass) {
        int shift = 56 - 8 * pass;
        hist[tid] = 0;
        __syncthreads();
        unsigned long long pref = s_pref;
        for (int i = tid; i < N_; i += 256) {
            unsigned long long key = kk[i];
            if (pass == 0 || (key >> (shift + 8)) == pref)
                atomicAdd(&hist[(unsigned int)((key >> shift) & 255ull)], 1u);
        }
        __syncthreads();
        if (tid == 0) {
            int cum = 0, bin = 0;
            for (; bin < 256; ++bin) {
                int c = (int)hist[bin];
                if (cum + c > s_rem) break;
                cum += c;
            }
            s_rem -= cum;
            s_pref = (pref << 8) | (unsigned long long)bin;
        }
        __syncthreads();
    }
    if (tid == 0) Tkey[b] = s_pref;
}

// ---- kernel 3: compact the exactly-PRE_ keys <= threshold (unordered; sorted next)
//      wave-aggregated atomics: one atomicAdd per wave instead of per thread
__global__ void k_compact(const unsigned long long* __restrict__ keys,
                          const unsigned long long* __restrict__ Tkey,
                          unsigned long long* __restrict__ cand,
                          unsigned int* __restrict__ cnt) {
    int b = blockIdx.y;
    int i = blockIdx.x * 256 + threadIdx.x;
    int lane = threadIdx.x & 63;
    bool pred = false;
    unsigned long long key = 0;
    if (i < N_) {
        key = keys[b * N_ + i];
        pred = (key <= Tkey[b]);
    }
    unsigned long long grp = __ballot(pred);
    if (grp) {
        int leader = __builtin_ctzll(grp);
        unsigned int base = 0;
        if (lane == leader)
            base = atomicAdd(&cnt[b], (unsigned int)__builtin_popcountll(grp));
        base = (unsigned int)__shfl((int)base, leader);
        if (pred) {
            unsigned int off = (unsigned int)__builtin_popcountll(grp & ((1ull << lane) - 1ull));
            unsigned int pos = base + off;
            if (pos < PRE_) cand[b * PRE_ + pos] = key;
        }
    }
}

// box decode exactly in the reference op order; no FMA contraction
__device__ __forceinline__ void compute_box(int b, unsigned int n,
                                            const float* __restrict__ deltas,
                                            const float* __restrict__ im_info,
                                            float box[4]) {
#pragma clang fp contract(off)
    int a   = (int)(n % A_);
    int pos = (int)(n / A_);
    int w   = pos % W_;
    int h   = pos / W_;
    float a0 = c_anchors[a][0] + (float)(w * 16);
    float a1 = c_anchors[a][1] + (float)(h * 16);
    float a2 = c_anchors[a][2] + (float)(w * 16);
    float a3 = c_anchors[a][3] + (float)(h * 16);
    float wa  = a2 - a0 + 1.f;
    float ha  = a3 - a1 + 1.f;
    float cxa = a0 + 0.5f * wa;
    float cya = a1 + 0.5f * ha;
    int base = ((b * 4 * A_ + a * 4) * H_ + h) * W_ + w;
    const int chs = H_ * W_;
    float dx = deltas[base];
    float dy = deltas[base + chs];
    float dw = deltas[base + 2 * chs];
    float dh = deltas[base + 3 * chs];
    float pcx = dx * wa + cxa;
    float pcy = dy * ha + cya;
    float pw  = expf(dw) * wa;
    float ph  = expf(dh) * ha;
    float x1 = pcx - 0.5f * pw;
    float y1 = pcy - 0.5f * ph;
    float x2 = pcx + 0.5f * pw;
    float y2 = pcy + 0.5f * ph;
    float imh = im_info[b * 3 + 0], imw = im_info[b * 3 + 1];
    x1 = fminf(fmaxf(x1, 0.f), imw - 1.f);
    x2 = fminf(fmaxf(x2, 0.f), imw - 1.f);
    y1 = fminf(fmaxf(y1, 0.f), imh - 1.f);
    y2 = fminf(fmaxf(y2, 0.f), imh - 1.f);
    box[0] = x1; box[1] = y1; box[2] = x2; box[3] = y2;
}

// ---- kernel 4: per-image bitonic sort of 8192 keys in LDS, then gather+decode boxes
__global__ __launch_bounds__(1024) void k_sort(const unsigned long long* __restrict__ cand,
                                               const float* __restrict__ deltas,
                                               const float* __restrict__ im_info,
                                               float* __restrict__ sboxes) {
    int b = blockIdx.x, tid = threadIdx.x;
    __shared__ unsigned long long sk[SORTN];   // 64 KB
    for (int i = tid; i < SORTN; i += 1024)
        sk[i] = (i < PRE_) ? cand[b * PRE_ + i] : ~0ull;
    __syncthreads();
    for (int k = 2; k <= SORTN; k <<= 1) {
        for (int j = k >> 1; j > 0; j >>= 1) {
            for (int i = tid; i < SORTN; i += 1024) {
                int ixj = i ^ j;
                if (ixj > i) {
                    unsigned long long x = sk[i], y = sk[ixj];
                    bool up = ((i & k) == 0);
                    if ((x > y) == up) { sk[i] = y; sk[ixj] = x; }
                }
            }
            __syncthreads();
        }
    }
    float4* sb4 = (float4*)sboxes;
    for (int i = tid; i < PRE_; i += 1024) {
        unsigned int n = (unsigned int)(sk[i] & 0xffffffffull);
        float box[4];
        compute_box(b, n, deltas, im_info, box);
        sb4[b * PRE_ + i] = make_float4(box[0], box[1], box[2], box[3]);
    }
}

// ---- kernel 5: exact greedy NMS, 1 wave per image, early-exit at 300 kept
__global__ __launch_bounds__(64) void k_nms(const float* __restrict__ sboxes,
                                            float* __restrict__ out) {
    int b = blockIdx.x, lane = threadIdx.x;
    __shared__ float kx1[POST_ + 64], ky1[POST_ + 64], kx2[POST_ + 64],
                     ky2[POST_ + 64], kar[POST_ + 64];
    const float4* bb = (const float4*)sboxes + b * PRE_;
    float* ob = out + b * POST_ * 5;
    int kept = 0;
    for (int blk = 0; blk < PRE_ && kept < POST_; blk += 64) {
        int idx = blk + lane;
        bool valid = idx < PRE_;
        float x1 = 0.f, y1 = 0.f, x2 = 0.f, y2 = 0.f;
        if (valid) { float4 v = bb[idx]; x1 = v.x; y1 = v.y; x2 = v.z; y2 = v.w; }
        float area = ((x2 - x1) + 1.f) * ((y2 - y1) + 1.f);
        bool sup = !valid;
        // suppression vs global kept list
        for (int kk = 0; kk < kept; ++kk) {
            float iw = fminf(x2, kx2[kk]) - fmaxf(x1, kx1[kk]) + 1.f;
            float ih = fminf(y2, ky2[kk]) - fmaxf(y1, ky1[kk]) + 1.f;
            iw = fmaxf(iw, 0.f); ih = fmaxf(ih, 0.f);
            float inter = iw * ih;
            float iou = inter / ((area + kar[kk]) - inter);
            sup = sup | (iou > 0.7f);
            if (((kk & 15) == 15) && __ballot(!sup) == 0ull) break;
        }
        // intra-block exact greedy via mask arithmetic
        unsigned long long alive = __ballot(!sup);
        unsigned long long keepm = 0ull;
        while (alive) {
            int i = __builtin_ctzll(alive);
            keepm |= (1ull << i);
            alive &= ~(1ull << i);
            float ix1 = __shfl(x1, i), iy1 = __shfl(y1, i);
            float ix2 = __shfl(x2, i), iy2 = __shfl(y2, i);
            float iar = __shfl(area, i);
            float iw = fminf(x2, ix2) - fmaxf(x1, ix1) + 1.f;
            float ih = fminf(y2, iy2) - fmaxf(y1, iy1) + 1.f;
            iw = fmaxf(iw, 0.f); ih = fmaxf(ih, 0.f);
            float inter = iw * ih;
            float iou = inter / ((area + iar) - inter);
            alive &= ~__ballot((lane > i) && (iou > 0.7f));
        }
        if ((keepm >> lane) & 1ull) {
            int my = kept + __builtin_popcountll(keepm & ((1ull << lane) - 1ull));
            kx1[my] = x1; ky1[my] = y1; kx2[my] = x2; ky2[my] = y2; kar[my] = area;
            if (my < POST_) {
                ob[my * 5 + 0] = (float)b;
                ob[my * 5 + 1] = x1; ob[my * 5 + 2] = y1;
                ob[my * 5 + 3] = x2; ob[my * 5 + 4] = y2;
            }
        }
        kept += __builtin_popcountll(keepm);
        __syncthreads();
    }
    int start = kept < POST_ ? kept : POST_;
    for (int r = start + lane; r < POST_; r += 64) {
        ob[r * 5 + 0] = (float)b;
        ob[r * 5 + 1] = 0.f; ob[r * 5 + 2] = 0.f;
        ob[r * 5 + 3] = 0.f; ob[r * 5 + 4] = 0.f;
    }
}

extern "C" void kernel_launch(void* const* d_in, const int* in_sizes, int n_in,
                              void* d_out, int out_size, void* d_ws, size_t ws_size,
                              hipStream_t stream) {
    const float* scores  = (const float*)d_in[0];
    const float* deltas  = (const float*)d_in[1];
    const float* im_info = (const float*)d_in[2];
    float* out = (float*)d_out;

    // workspace layout
    char* ws = (char*)d_ws;
    unsigned long long* keys = (unsigned long long*)(ws);                  // B*N*8      = 1,094,400
    unsigned long long* cand = (unsigned long long*)(ws + 1094400);        // B*PRE*8    =   192,000
    unsigned long long* Tkey = (unsigned long long*)(ws + 1286400);        // B*8        =        32
    unsigned int*       cnt  = (unsigned int*)      (ws + 1286432);        // B*4        =        16
    float*              sbx  = (float*)             (ws + 1286448);        // B*PRE*4*4  =   384,000

    hipMemsetAsync(cnt, 0, B_ * sizeof(unsigned int), stream);

    const int total = B_ * A_ * H_ * W_;
    k_keys<<<(total + 255) / 256, 256, 0, stream>>>(scores, keys);
    k_select<<<B_, 256, 0, stream>>>(keys, Tkey);
    dim3 cgrid((N_ + 255) / 256, B_);
    k_compact<<<cgrid, 256, 0, stream>>>(keys, Tkey, cand, cnt);
    k_sort<<<B_, 1024, 0, stream>>>(cand, deltas, im_info, sbx);
    k_nms<<<B_, 64, 0, stream>>>(sbx, out);
}

// Round 3
// 391.350 us; speedup vs baseline: 2.0643x; 1.4339x over previous
//
#include <hip/hip_runtime.h>
#include <stdint.h>

#define B_    4
#define A_    9
#define H_    50
#define W_    76
#define N_    (H_ * W_ * A_)   // 34200
#define PRE_  6000
#define POST_ 300
#define SORTN 8192
#define BCAP  8192

// generate_anchors(16) precomputed (exact, verified against the numpy code)
__constant__ float c_anchors[9][4] = {
    { -84.f,  -40.f,  99.f,  55.f},
    {-176.f,  -88.f, 191.f, 103.f},
    {-360.f, -184.f, 375.f, 199.f},
    { -56.f,  -56.f,  71.f,  71.f},
    {-120.f, -120.f, 135.f, 135.f},
    {-248.f, -248.f, 263.f, 263.f},
    { -36.f,  -80.f,  51.f,  95.f},
    { -80.f, -168.f,  95.f, 183.f},
    {-168.f, -344.f, 183.f, 359.f},
};

// ---- kernel 1: composite keys (~score_bits)<<32 | n, plus 16-bit-prefix histogram
__global__ void k_keys_hist(const float* __restrict__ scores,
                            unsigned long long* __restrict__ keys,
                            unsigned int* __restrict__ hist) {
    int idx = blockIdx.x * 256 + threadIdx.x;
    const int total = B_ * A_ * H_ * W_;
    if (idx >= total) return;
    int w = idx % W_;
    int h = (idx / W_) % H_;
    int a = (idx / (W_ * H_)) % A_;
    int b = idx / (W_ * H_ * A_);
    float s = scores[(((b * 2 * A_) + A_ + a) * H_ + h) * W_ + w];
    unsigned int sb = __float_as_uint(s);          // s >= 0 -> monotone bits
    unsigned int n  = (unsigned int)((h * W_ + w) * A_ + a);
    unsigned long long key = (((unsigned long long)(~sb)) << 32) | (unsigned long long)n;
    keys[b * N_ + n] = key;
    atomicAdd(&hist[b * 65536 + (unsigned int)(key >> 48)], 1u);
}

// ---- kernel 2: find the 16-bit bucket containing rank PRE_-1, and residual rank
__global__ __launch_bounds__(256) void k_scan(const unsigned int* __restrict__ hist,
                                              unsigned int* __restrict__ T16,
                                              unsigned int* __restrict__ rem) {
    int b = blockIdx.x, tid = threadIdx.x;
    const unsigned int* h = hist + b * 65536;
    __shared__ unsigned int part[256];
    __shared__ unsigned int bins[256];
    __shared__ unsigned int s_seg, s_rem1;
    unsigned int sum = 0;
    for (int i = 0; i < 256; ++i) sum += h[tid * 256 + i];
    part[tid] = sum;
    __syncthreads();
    if (tid == 0) {
        unsigned int cum = 0; int seg = 0;
        for (; seg < 256; ++seg) {
            unsigned int c = part[seg];
            if (cum + c > (unsigned int)(PRE_ - 1)) break;
            cum += c;
        }
        s_seg = (unsigned int)seg;
        s_rem1 = (unsigned int)(PRE_ - 1) - cum;
    }
    __syncthreads();
    bins[tid] = h[s_seg * 256 + tid];
    __syncthreads();
    if (tid == 0) {
        unsigned int cum = 0; int bin = 0; unsigned int r = s_rem1;
        for (; bin < 256; ++bin) {
            unsigned int c = bins[bin];
            if (cum + c > r) break;
            cum += c;
        }
        T16[b] = s_seg * 256 + (unsigned int)bin;
        rem[b] = r - cum;
    }
}

// ---- kernel 3: compact keys whose top-16 == T16 (wave-aggregated atomics)
__global__ void k_bucket(const unsigned long long* __restrict__ keys,
                         const unsigned int* __restrict__ T16,
                         unsigned long long* __restrict__ bucket,
                         unsigned int* __restrict__ bcnt) {
    int b = blockIdx.y;
    int i = blockIdx.x * 256 + threadIdx.x;
    int lane = threadIdx.x & 63;
    bool pred = false;
    unsigned long long key = 0;
    if (i < N_) {
        key = keys[b * N_ + i];
        pred = ((unsigned int)(key >> 48) == T16[b]);
    }
    unsigned long long grp = __ballot(pred);
    if (grp) {
        int leader = __builtin_ctzll(grp);
        unsigned int base = 0;
        if (lane == leader)
            base = atomicAdd(&bcnt[b], (unsigned int)__builtin_popcountll(grp));
        base = (unsigned int)__shfl((int)base, leader);
        if (pred) {
            unsigned int pos = base + (unsigned int)__builtin_popcountll(grp & ((1ull << lane) - 1ull));
            if (pos < BCAP) bucket[b * BCAP + pos] = key;
        }
    }
}

// ---- kernel 4: exact rank-by-counting within the bucket -> threshold key
__global__ __launch_bounds__(256) void k_sel2(const unsigned long long* __restrict__ bucket,
                                              const unsigned int* __restrict__ bcnt,
                                              const unsigned int* __restrict__ rem,
                                              unsigned long long* __restrict__ Tkey) {
    int b = blockIdx.x, tid = threadIdx.x;
    __shared__ unsigned long long sb[BCAP];   // 64 KB
    unsigned int count = bcnt[b];
    if (count > BCAP) count = BCAP;
    for (unsigned int i = tid; i < count; i += 256) sb[i] = bucket[b * BCAP + i];
    __syncthreads();
    unsigned int target = rem[b];
    for (unsigned int e = tid; e < count; e += 256) {
        unsigned long long k = sb[e];
        unsigned int r = 0;
        for (unsigned int j = 0; j < count; ++j) r += (sb[j] < k) ? 1u : 0u;
        if (r == target) Tkey[b] = k;
    }
}

// ---- kernel 5: compact the exactly-PRE_ keys <= threshold (unordered; sorted next)
__global__ void k_compact(const unsigned long long* __restrict__ keys,
                          const unsigned long long* __restrict__ Tkey,
                          unsigned long long* __restrict__ cand,
                          unsigned int* __restrict__ cnt) {
    int b = blockIdx.y;
    int i = blockIdx.x * 256 + threadIdx.x;
    int lane = threadIdx.x & 63;
    bool pred = false;
    unsigned long long key = 0;
    if (i < N_) {
        key = keys[b * N_ + i];
        pred = (key <= Tkey[b]);
    }
    unsigned long long grp = __ballot(pred);
    if (grp) {
        int leader = __builtin_ctzll(grp);
        unsigned int base = 0;
        if (lane == leader)
            base = atomicAdd(&cnt[b], (unsigned int)__builtin_popcountll(grp));
        base = (unsigned int)__shfl((int)base, leader);
        if (pred) {
            unsigned int pos = base + (unsigned int)__builtin_popcountll(grp & ((1ull << lane) - 1ull));
            if (pos < PRE_) cand[b * PRE_ + pos] = key;
        }
    }
}

// box decode exactly in the reference op order; no FMA contraction
__device__ __forceinline__ void compute_box(int b, unsigned int n,
                                            const float* __restrict__ deltas,
                                            const float* __restrict__ im_info,
                                            float box[4]) {
#pragma clang fp contract(off)
    int a   = (int)(n % A_);
    int pos = (int)(n / A_);
    int w   = pos % W_;
    int h   = pos / W_;
    float a0 = c_anchors[a][0] + (float)(w * 16);
    float a1 = c_anchors[a][1] + (float)(h * 16);
    float a2 = c_anchors[a][2] + (float)(w * 16);
    float a3 = c_anchors[a][3] + (float)(h * 16);
    float wa  = a2 - a0 + 1.f;
    float ha  = a3 - a1 + 1.f;
    float cxa = a0 + 0.5f * wa;
    float cya = a1 + 0.5f * ha;
    int base = ((b * 4 * A_ + a * 4) * H_ + h) * W_ + w;
    const int chs = H_ * W_;
    float dx = deltas[base];
    float dy = deltas[base + chs];
    float dw = deltas[base + 2 * chs];
    float dh = deltas[base + 3 * chs];
    float pcx = dx * wa + cxa;
    float pcy = dy * ha + cya;
    float pw  = expf(dw) * wa;
    float ph  = expf(dh) * ha;
    float x1 = pcx - 0.5f * pw;
    float y1 = pcy - 0.5f * ph;
    float x2 = pcx + 0.5f * pw;
    float y2 = pcy + 0.5f * ph;
    float imh = im_info[b * 3 + 0], imw = im_info[b * 3 + 1];
    x1 = fminf(fmaxf(x1, 0.f), imw - 1.f);
    x2 = fminf(fmaxf(x2, 0.f), imw - 1.f);
    y1 = fminf(fmaxf(y1, 0.f), imh - 1.f);
    y2 = fminf(fmaxf(y2, 0.f), imh - 1.f);
    box[0] = x1; box[1] = y1; box[2] = x2; box[3] = y2;
}

// ---- kernel 6: per-image bitonic sort of 8192 keys in LDS, then gather+decode boxes
__global__ __launch_bounds__(1024) void k_sort(const unsigned long long* __restrict__ cand,
                                               const float* __restrict__ deltas,
                                               const float* __restrict__ im_info,
                                               float* __restrict__ sboxes) {
    int b = blockIdx.x, tid = threadIdx.x;
    __shared__ unsigned long long sk[SORTN];   // 64 KB
    for (int i = tid; i < SORTN; i += 1024)
        sk[i] = (i < PRE_) ? cand[b * PRE_ + i] : ~0ull;
    __syncthreads();
    for (int k = 2; k <= SORTN; k <<= 1) {
        for (int j = k >> 1; j > 0; j >>= 1) {
            for (int i = tid; i < SORTN; i += 1024) {
                int ixj = i ^ j;
                if (ixj > i) {
                    unsigned long long x = sk[i], y = sk[ixj];
                    bool up = ((i & k) == 0);
                    if ((x > y) == up) { sk[i] = y; sk[ixj] = x; }
                }
            }
            __syncthreads();
        }
    }
    float4* sb4 = (float4*)sboxes;
    for (int i = tid; i < PRE_; i += 1024) {
        unsigned int n = (unsigned int)(sk[i] & 0xffffffffull);
        float box[4];
        compute_box(b, n, deltas, im_info, box);
        sb4[b * PRE_ + i] = make_float4(box[0], box[1], box[2], box[3]);
    }
}

// ---- kernel 7: exact greedy NMS, 1 wave per image, early-exit at 300 kept
__global__ __launch_bounds__(64) void k_nms(const float* __restrict__ sboxes,
                                            float* __restrict__ out) {
    int b = blockIdx.x, lane = threadIdx.x;
    __shared__ float kx1[POST_ + 64], ky1[POST_ + 64], kx2[POST_ + 64],
                     ky2[POST_ + 64], kar[POST_ + 64];
    const float4* bb = (const float4*)sboxes + b * PRE_;
    float* ob = out + b * POST_ * 5;
    int kept = 0;
    for (int blk = 0; blk < PRE_ && kept < POST_; blk += 64) {
        int idx = blk + lane;
        bool valid = idx < PRE_;
        float x1 = 0.f, y1 = 0.f, x2 = 0.f, y2 = 0.f;
        if (valid) { float4 v = bb[idx]; x1 = v.x; y1 = v.y; x2 = v.z; y2 = v.w; }
        float area = ((x2 - x1) + 1.f) * ((y2 - y1) + 1.f);
        bool sup = !valid;
        for (int kk = 0; kk < kept; ++kk) {
            float iw = fminf(x2, kx2[kk]) - fmaxf(x1, kx1[kk]) + 1.f;
            float ih = fminf(y2, ky2[kk]) - fmaxf(y1, ky1[kk]) + 1.f;
            iw = fmaxf(iw, 0.f); ih = fmaxf(ih, 0.f);
            float inter = iw * ih;
            float iou = inter / ((area + kar[kk]) - inter);
            sup = sup | (iou > 0.7f);
            if (((kk & 15) == 15) && __ballot(!sup) == 0ull) break;
        }
        unsigned long long alive = __ballot(!sup);
        unsigned long long keepm = 0ull;
        while (alive) {
            int i = __builtin_ctzll(alive);
            keepm |= (1ull << i);
            alive &= ~(1ull << i);
            float ix1 = __shfl(x1, i), iy1 = __shfl(y1, i);
            float ix2 = __shfl(x2, i), iy2 = __shfl(y2, i);
            float iar = __shfl(area, i);
            float iw = fminf(x2, ix2) - fmaxf(x1, ix1) + 1.f;
            float ih = fminf(y2, iy2) - fmaxf(y1, iy1) + 1.f;
            iw = fmaxf(iw, 0.f); ih = fmaxf(ih, 0.f);
            float inter = iw * ih;
            float iou = inter / ((area + iar) - inter);
            alive &= ~__ballot((lane > i) && (iou > 0.7f));
        }
        if ((keepm >> lane) & 1ull) {
            int my = kept + __builtin_popcountll(keepm & ((1ull << lane) - 1ull));
            kx1[my] = x1; ky1[my] = y1; kx2[my] = x2; ky2[my] = y2; kar[my] = area;
            if (my < POST_) {
                ob[my * 5 + 0] = (float)b;
                ob[my * 5 + 1] = x1; ob[my * 5 + 2] = y1;
                ob[my * 5 + 3] = x2; ob[my * 5 + 4] = y2;
            }
        }
        kept += __builtin_popcountll(keepm);
        __syncthreads();
    }
    int start = kept < POST_ ? kept : POST_;
    for (int r = start + lane; r < POST_; r += 64) {
        ob[r * 5 + 0] = (float)b;
        ob[r * 5 + 1] = 0.f; ob[r * 5 + 2] = 0.f;
        ob[r * 5 + 3] = 0.f; ob[r * 5 + 4] = 0.f;
    }
}

extern "C" void kernel_launch(void* const* d_in, const int* in_sizes, int n_in,
                              void* d_out, int out_size, void* d_ws, size_t ws_size,
                              hipStream_t stream) {
    const float* scores  = (const float*)d_in[0];
    const float* deltas  = (const float*)d_in[1];
    const float* im_info = (const float*)d_in[2];
    float* out = (float*)d_out;

    // workspace layout (all 8-aligned)
    char* ws = (char*)d_ws;
    unsigned long long* keys   = (unsigned long long*)(ws);                 // 1,094,400
    unsigned int*       hist   = (unsigned int*)      (ws + 1094400);       // 1,048,576
    unsigned long long* bucket = (unsigned long long*)(ws + 2142976);       //   262,144
    unsigned int*       ctrs   = (unsigned int*)      (ws + 2405120);       //        32 (bcnt[4], cnt[4])
    unsigned int*       T16    = (unsigned int*)      (ws + 2405152);       //        16
    unsigned int*       rem    = (unsigned int*)      (ws + 2405168);       //        16
    unsigned long long* Tkey   = (unsigned long long*)(ws + 2405184);       //        32
    unsigned long long* cand   = (unsigned long long*)(ws + 2405216);       //   192,000
    float*              sbx    = (float*)             (ws + 2597216);       //   384,000
    unsigned int* bcnt = ctrs;
    unsigned int* cnt  = ctrs + B_;

    hipMemsetAsync(hist, 0, B_ * 65536 * sizeof(unsigned int), stream);
    hipMemsetAsync(ctrs, 0, 2 * B_ * sizeof(unsigned int), stream);

    const int total = B_ * A_ * H_ * W_;
    dim3 g2d((N_ + 255) / 256, B_);
    k_keys_hist<<<(total + 255) / 256, 256, 0, stream>>>(scores, keys, hist);
    k_scan<<<B_, 256, 0, stream>>>(hist, T16, rem);
    k_bucket<<<g2d, 256, 0, stream>>>(keys, T16, bucket, bcnt);
    k_sel2<<<B_, 256, 0, stream>>>(bucket, bcnt, rem, Tkey);
    k_compact<<<g2d, 256, 0, stream>>>(keys, Tkey, cand, cnt);
    k_sort<<<B_, 1024, 0, stream>>>(cand, deltas, im_info, sbx);
    k_nms<<<B_, 64, 0, stream>>>(sbx, out);
}

// Round 4
// 291.819 us; speedup vs baseline: 2.7683x; 1.3411x over previous
//
#include <hip/hip_runtime.h>
#include <stdint.h>

#define B_    4
#define A_    9
#define H_    50
#define W_    76
#define N_    (H_ * W_ * A_)   // 34200
#define PRE_  6000
#define POST_ 300
#define SORTN 8192
#define BCAP  8192

// generate_anchors(16) precomputed (exact, verified against the numpy code)
__constant__ float c_anchors[9][4] = {
    { -84.f,  -40.f,  99.f,  55.f},
    {-176.f,  -88.f, 191.f, 103.f},
    {-360.f, -184.f, 375.f, 199.f},
    { -56.f,  -56.f,  71.f,  71.f},
    {-120.f, -120.f, 135.f, 135.f},
    {-248.f, -248.f, 263.f, 263.f},
    { -36.f,  -80.f,  51.f,  95.f},
    { -80.f, -168.f,  95.f, 183.f},
    {-168.f, -344.f, 183.f, 359.f},
};

// ---- kernel 1: composite keys (~score_bits)<<32 | n, plus 16-bit-prefix histogram
__global__ void k_keys_hist(const float* __restrict__ scores,
                            unsigned long long* __restrict__ keys,
                            unsigned int* __restrict__ hist) {
    int idx = blockIdx.x * 256 + threadIdx.x;
    const int total = B_ * A_ * H_ * W_;
    if (idx >= total) return;
    int w = idx % W_;
    int h = (idx / W_) % H_;
    int a = (idx / (W_ * H_)) % A_;
    int b = idx / (W_ * H_ * A_);
    float s = scores[(((b * 2 * A_) + A_ + a) * H_ + h) * W_ + w];
    unsigned int sb = __float_as_uint(s);          // s >= 0 -> monotone bits
    unsigned int n  = (unsigned int)((h * W_ + w) * A_ + a);
    unsigned long long key = (((unsigned long long)(~sb)) << 32) | (unsigned long long)n;
    keys[b * N_ + n] = key;
    atomicAdd(&hist[b * 65536 + (unsigned int)(key >> 48)], 1u);
}

// ---- kernel 2: find the 16-bit bucket containing rank PRE_-1, and residual rank
__global__ __launch_bounds__(256) void k_scan(const unsigned int* __restrict__ hist,
                                              unsigned int* __restrict__ T16,
                                              unsigned int* __restrict__ rem) {
    int b = blockIdx.x, tid = threadIdx.x;
    const unsigned int* h = hist + b * 65536;
    __shared__ unsigned int part[256];
    __shared__ unsigned int bins[256];
    __shared__ unsigned int s_seg, s_rem1;
    unsigned int sum = 0;
    for (int i = 0; i < 256; ++i) sum += h[tid * 256 + i];
    part[tid] = sum;
    __syncthreads();
    if (tid == 0) {
        unsigned int cum = 0; int seg = 0;
        for (; seg < 256; ++seg) {
            unsigned int c = part[seg];
            if (cum + c > (unsigned int)(PRE_ - 1)) break;
            cum += c;
        }
        s_seg = (unsigned int)seg;
        s_rem1 = (unsigned int)(PRE_ - 1) - cum;
    }
    __syncthreads();
    bins[tid] = h[s_seg * 256 + tid];
    __syncthreads();
    if (tid == 0) {
        unsigned int cum = 0; int bin = 0; unsigned int r = s_rem1;
        for (; bin < 256; ++bin) {
            unsigned int c = bins[bin];
            if (cum + c > r) break;
            cum += c;
        }
        T16[b] = s_seg * 256 + (unsigned int)bin;
        rem[b] = r - cum;
    }
}

// ---- kernel 3: compact keys whose top-16 == T16 (wave-aggregated atomics)
__global__ void k_bucket(const unsigned long long* __restrict__ keys,
                         const unsigned int* __restrict__ T16,
                         unsigned long long* __restrict__ bucket,
                         unsigned int* __restrict__ bcnt) {
    int b = blockIdx.y;
    int i = blockIdx.x * 256 + threadIdx.x;
    int lane = threadIdx.x & 63;
    bool pred = false;
    unsigned long long key = 0;
    if (i < N_) {
        key = keys[b * N_ + i];
        pred = ((unsigned int)(key >> 48) == T16[b]);
    }
    unsigned long long grp = __ballot(pred);
    if (grp) {
        int leader = __builtin_ctzll(grp);
        unsigned int base = 0;
        if (lane == leader)
            base = atomicAdd(&bcnt[b], (unsigned int)__builtin_popcountll(grp));
        base = (unsigned int)__shfl((int)base, leader);
        if (pred) {
            unsigned int pos = base + (unsigned int)__builtin_popcountll(grp & ((1ull << lane) - 1ull));
            if (pos < BCAP) bucket[b * BCAP + pos] = key;
        }
    }
}

// ---- kernel 4: exact rank-by-counting within the bucket -> threshold key
__global__ __launch_bounds__(256) void k_sel2(const unsigned long long* __restrict__ bucket,
                                              const unsigned int* __restrict__ bcnt,
                                              const unsigned int* __restrict__ rem,
                                              unsigned long long* __restrict__ Tkey) {
    int b = blockIdx.x, tid = threadIdx.x;
    __shared__ unsigned long long sb[BCAP];   // 64 KB
    unsigned int count = bcnt[b];
    if (count > BCAP) count = BCAP;
    for (unsigned int i = tid; i < count; i += 256) sb[i] = bucket[b * BCAP + i];
    __syncthreads();
    unsigned int target = rem[b];
    for (unsigned int e = tid; e < count; e += 256) {
        unsigned long long k = sb[e];
        unsigned int r = 0;
        for (unsigned int j = 0; j < count; ++j) r += (sb[j] < k) ? 1u : 0u;
        if (r == target) Tkey[b] = k;
    }
}

// ---- kernel 5: compact the exactly-PRE_ keys <= threshold (unordered; sorted next)
__global__ void k_compact(const unsigned long long* __restrict__ keys,
                          const unsigned long long* __restrict__ Tkey,
                          unsigned long long* __restrict__ cand,
                          unsigned int* __restrict__ cnt) {
    int b = blockIdx.y;
    int i = blockIdx.x * 256 + threadIdx.x;
    int lane = threadIdx.x & 63;
    bool pred = false;
    unsigned long long key = 0;
    if (i < N_) {
        key = keys[b * N_ + i];
        pred = (key <= Tkey[b]);
    }
    unsigned long long grp = __ballot(pred);
    if (grp) {
        int leader = __builtin_ctzll(grp);
        unsigned int base = 0;
        if (lane == leader)
            base = atomicAdd(&cnt[b], (unsigned int)__builtin_popcountll(grp));
        base = (unsigned int)__shfl((int)base, leader);
        if (pred) {
            unsigned int pos = base + (unsigned int)__builtin_popcountll(grp & ((1ull << lane) - 1ull));
            if (pos < PRE_) cand[b * PRE_ + pos] = key;
        }
    }
}

// box decode exactly in the reference op order; no FMA contraction
__device__ __forceinline__ void compute_box(int b, unsigned int n,
                                            const float* __restrict__ deltas,
                                            const float* __restrict__ im_info,
                                            float box[4]) {
#pragma clang fp contract(off)
    int a   = (int)(n % A_);
    int pos = (int)(n / A_);
    int w   = pos % W_;
    int h   = pos / W_;
    float a0 = c_anchors[a][0] + (float)(w * 16);
    float a1 = c_anchors[a][1] + (float)(h * 16);
    float a2 = c_anchors[a][2] + (float)(w * 16);
    float a3 = c_anchors[a][3] + (float)(h * 16);
    float wa  = a2 - a0 + 1.f;
    float ha  = a3 - a1 + 1.f;
    float cxa = a0 + 0.5f * wa;
    float cya = a1 + 0.5f * ha;
    int base = ((b * 4 * A_ + a * 4) * H_ + h) * W_ + w;
    const int chs = H_ * W_;
    float dx = deltas[base];
    float dy = deltas[base + chs];
    float dw = deltas[base + 2 * chs];
    float dh = deltas[base + 3 * chs];
    float pcx = dx * wa + cxa;
    float pcy = dy * ha + cya;
    float pw  = expf(dw) * wa;
    float ph  = expf(dh) * ha;
    float x1 = pcx - 0.5f * pw;
    float y1 = pcy - 0.5f * ph;
    float x2 = pcx + 0.5f * pw;
    float y2 = pcy + 0.5f * ph;
    float imh = im_info[b * 3 + 0], imw = im_info[b * 3 + 1];
    x1 = fminf(fmaxf(x1, 0.f), imw - 1.f);
    x2 = fminf(fmaxf(x2, 0.f), imw - 1.f);
    y1 = fminf(fmaxf(y1, 0.f), imh - 1.f);
    y2 = fminf(fmaxf(y2, 0.f), imh - 1.f);
    box[0] = x1; box[1] = y1; box[2] = x2; box[3] = y2;
}

// ---- kernel 6: per-image bitonic sort of 8192 keys in LDS, then gather+decode boxes
__global__ __launch_bounds__(1024) void k_sort(const unsigned long long* __restrict__ cand,
                                               const float* __restrict__ deltas,
                                               const float* __restrict__ im_info,
                                               float* __restrict__ sboxes) {
    int b = blockIdx.x, tid = threadIdx.x;
    __shared__ unsigned long long sk[SORTN];   // 64 KB
    for (int i = tid; i < SORTN; i += 1024)
        sk[i] = (i < PRE_) ? cand[b * PRE_ + i] : ~0ull;
    __syncthreads();
    for (int k = 2; k <= SORTN; k <<= 1) {
        for (int j = k >> 1; j > 0; j >>= 1) {
            for (int i = tid; i < SORTN; i += 1024) {
                int ixj = i ^ j;
                if (ixj > i) {
                    unsigned long long x = sk[i], y = sk[ixj];
                    bool up = ((i & k) == 0);
                    if ((x > y) == up) { sk[i] = y; sk[ixj] = x; }
                }
            }
            __syncthreads();
        }
    }
    float4* sb4 = (float4*)sboxes;
    for (int i = tid; i < PRE_; i += 1024) {
        unsigned int n = (unsigned int)(sk[i] & 0xffffffffull);
        float box[4];
        compute_box(b, n, deltas, im_info, box);
        sb4[b * PRE_ + i] = make_float4(box[0], box[1], box[2], box[3]);
    }
}

// ---- kernel 7: exact greedy NMS, 16 waves per image
//      phase a: kept-list check split across 16 waves (each wave strides the kept list)
//      phase b: intra-64 greedy via ballot/shfl mask arithmetic on wave 0
__global__ __launch_bounds__(1024) void k_nms(const float* __restrict__ sboxes,
                                              float* __restrict__ out) {
    int b = blockIdx.x;
    int tid = threadIdx.x;
    int lane = tid & 63;
    int wave = tid >> 6;                 // 0..15
    __shared__ float4 s_box[POST_ + 64];
    __shared__ float  s_ar [POST_ + 64];
    __shared__ unsigned long long s_supw[16];
    __shared__ int s_kept;
    if (tid == 0) s_kept = 0;
    __syncthreads();

    const float4* bb = (const float4*)sboxes + b * PRE_;
    float* ob = out + b * POST_ * 5;

    for (int blk = 0; blk < PRE_; blk += 64) {
        int kept = s_kept;               // uniform (post-barrier)
        if (kept >= POST_) break;
        int idx = blk + lane;
        bool valid = idx < PRE_;
        float4 v = make_float4(0.f, 0.f, 0.f, 0.f);
        if (valid) v = bb[idx];
        float area = ((v.z - v.x) + 1.f) * ((v.w - v.y) + 1.f);
        bool sup = !valid;
        // phase a: each wave checks kept indices wave, wave+16, ...
        for (int kk = wave; kk < kept; kk += 16) {
            float4 kb = s_box[kk];
            float iw = fminf(v.z, kb.z) - fmaxf(v.x, kb.x) + 1.f;
            float ih = fminf(v.w, kb.w) - fmaxf(v.y, kb.y) + 1.f;
            iw = fmaxf(iw, 0.f); ih = fmaxf(ih, 0.f);
            float inter = iw * ih;
            float iou = inter / ((area + s_ar[kk]) - inter);
            sup = sup | (iou > 0.7f);
        }
        unsigned long long wm = __ballot(sup);
        if (lane == 0) s_supw[wave] = wm;
        __syncthreads();
        if (wave == 0) {
            unsigned long long supm = 0ull;
#pragma unroll
            for (int w2 = 0; w2 < 16; ++w2) supm |= s_supw[w2];
            // phase b: exact greedy within the 64 survivors
            unsigned long long alive = ~supm;
            unsigned long long keepm = 0ull;
            while (alive) {
                int i = __builtin_ctzll(alive);
                keepm |= (1ull << i);
                alive &= ~(1ull << i);
                float ix1 = __shfl(v.x, i), iy1 = __shfl(v.y, i);
                float ix2 = __shfl(v.z, i), iy2 = __shfl(v.w, i);
                float iar = __shfl(area, i);
                float iw = fminf(v.z, ix2) - fmaxf(v.x, ix1) + 1.f;
                float ih = fminf(v.w, iy2) - fmaxf(v.y, iy1) + 1.f;
                iw = fmaxf(iw, 0.f); ih = fmaxf(ih, 0.f);
                float inter = iw * ih;
                float iou = inter / ((area + iar) - inter);
                alive &= ~__ballot((lane > i) && (iou > 0.7f));
            }
            if ((keepm >> lane) & 1ull) {
                int my = kept + __builtin_popcountll(keepm & ((1ull << lane) - 1ull));
                s_box[my] = v;
                s_ar [my] = area;
                if (my < POST_) {
                    ob[my * 5 + 0] = (float)b;
                    ob[my * 5 + 1] = v.x; ob[my * 5 + 2] = v.y;
                    ob[my * 5 + 3] = v.z; ob[my * 5 + 4] = v.w;
                }
            }
            if (lane == 0) s_kept = kept + __builtin_popcountll(keepm);
        }
        __syncthreads();
    }
    // zero-fill rows beyond the kept count
    int kept = s_kept;
    int start = kept < POST_ ? kept : POST_;
    for (int r = start + tid; r < POST_; r += 1024) {
        ob[r * 5 + 0] = (float)b;
        ob[r * 5 + 1] = 0.f; ob[r * 5 + 2] = 0.f;
        ob[r * 5 + 3] = 0.f; ob[r * 5 + 4] = 0.f;
    }
}

extern "C" void kernel_launch(void* const* d_in, const int* in_sizes, int n_in,
                              void* d_out, int out_size, void* d_ws, size_t ws_size,
                              hipStream_t stream) {
    const float* scores  = (const float*)d_in[0];
    const float* deltas  = (const float*)d_in[1];
    const float* im_info = (const float*)d_in[2];
    float* out = (float*)d_out;

    // workspace layout (all 8-aligned)
    char* ws = (char*)d_ws;
    unsigned long long* keys   = (unsigned long long*)(ws);                 // 1,094,400
    unsigned int*       hist   = (unsigned int*)      (ws + 1094400);       // 1,048,576
    unsigned long long* bucket = (unsigned long long*)(ws + 2142976);       //   262,144
    unsigned int*       ctrs   = (unsigned int*)      (ws + 2405120);       //        32 (bcnt[4], cnt[4])
    unsigned int*       T16    = (unsigned int*)      (ws + 2405152);       //        16
    unsigned int*       rem    = (unsigned int*)      (ws + 2405168);       //        16
    unsigned long long* Tkey   = (unsigned long long*)(ws + 2405184);       //        32
    unsigned long long* cand   = (unsigned long long*)(ws + 2405216);       //   192,000
    float*              sbx    = (float*)             (ws + 2597216);       //   384,000
    unsigned int* bcnt = ctrs;
    unsigned int* cnt  = ctrs + B_;

    hipMemsetAsync(hist, 0, B_ * 65536 * sizeof(unsigned int), stream);
    hipMemsetAsync(ctrs, 0, 2 * B_ * sizeof(unsigned int), stream);

    const int total = B_ * A_ * H_ * W_;
    dim3 g2d((N_ + 255) / 256, B_);
    k_keys_hist<<<(total + 255) / 256, 256, 0, stream>>>(scores, keys, hist);
    k_scan<<<B_, 256, 0, stream>>>(hist, T16, rem);
    k_bucket<<<g2d, 256, 0, stream>>>(keys, T16, bucket, bcnt);
    k_sel2<<<B_, 256, 0, stream>>>(bucket, bcnt, rem, Tkey);
    k_compact<<<g2d, 256, 0, stream>>>(keys, Tkey, cand, cnt);
    k_sort<<<B_, 1024, 0, stream>>>(cand, deltas, im_info, sbx);
    k_nms<<<B_, 1024, 0, stream>>>(sbx, out);
}

// Round 5
// 235.259 us; speedup vs baseline: 3.4339x; 1.2404x over previous
//
#include <hip/hip_runtime.h>
#include <stdint.h>

#define B_     4
#define A_     9
#define H_     50
#define W_     76
#define N_     (H_ * W_ * A_)   // 34200
#define PRE_   6000
#define POST_  300
#define NBIN   65536
#define SKCAP  8192
#define ACTMAX 256
#define FXCAP  2048

// generate_anchors(16) precomputed (exact, verified against the numpy code)
__constant__ float c_anchors[9][4] = {
    { -84.f,  -40.f,  99.f,  55.f},
    {-176.f,  -88.f, 191.f, 103.f},
    {-360.f, -184.f, 375.f, 199.f},
    { -56.f,  -56.f,  71.f,  71.f},
    {-120.f, -120.f, 135.f, 135.f},
    {-248.f, -248.f, 263.f, 263.f},
    { -36.f,  -80.f,  51.f,  95.f},
    { -80.f, -168.f,  95.f, 183.f},
    {-168.f, -344.f, 183.f, 359.f},
};

// composite key: (~score_bits)<<32 | n  — ascending key == descending score, ascending idx
__device__ __forceinline__ unsigned long long make_key(const float* __restrict__ scores,
                                                       int idx, int* pb) {
    int w = idx % W_;
    int h = (idx / W_) % H_;
    int a = (idx / (W_ * H_)) % A_;
    int b = idx / (W_ * H_ * A_);
    float s = scores[(((b * 2 * A_) + A_ + a) * H_ + h) * W_ + w];
    unsigned int sb = __float_as_uint(s);          // s >= 0 -> monotone bits
    unsigned int n  = (unsigned int)((h * W_ + w) * A_ + a);
    *pb = b;
    return (((unsigned long long)(~sb)) << 32) | (unsigned long long)n;
}

// ---- kernel 1: 16-bit-prefix histogram of keys
__global__ void k_hist(const float* __restrict__ scores,
                       unsigned int* __restrict__ hist) {
    int idx = blockIdx.x * 256 + threadIdx.x;
    if (idx >= B_ * N_) return;
    int b;
    unsigned long long key = make_key(scores, idx, &b);
    atomicAdd(&hist[b * NBIN + (unsigned int)(key >> 48)], 1u);
}

// ---- kernel 2: exclusive prefix over 65536 bins (in place + working copy),
//      emit active buckets (start < PRE_ && cnt > 0)
__global__ __launch_bounds__(1024) void k_prefix(unsigned int* __restrict__ hist,
                                                 unsigned int* __restrict__ prefw,
                                                 unsigned int* __restrict__ actA,
                                                 unsigned int* __restrict__ actB,
                                                 unsigned int* __restrict__ actcnt) {
    int b = blockIdx.x, tid = threadIdx.x;
    unsigned int* hb = hist + b * NBIN;
    unsigned int* pw = prefw + b * NBIN;
    const uint4* seg = (const uint4*)(hb + tid * 64);
    // pass 1: per-thread segment sum (64 bins, vectorized)
    unsigned int sum = 0;
#pragma unroll
    for (int i = 0; i < 16; ++i) {
        uint4 v = seg[i];
        sum += v.x + v.y + v.z + v.w;
    }
    // block scan (Hillis-Steele, inclusive) -> exclusive base
    __shared__ unsigned int sp[1024];
    sp[tid] = sum;
    __syncthreads();
    for (int off = 1; off < 1024; off <<= 1) {
        unsigned int v = (tid >= off) ? sp[tid - off] : 0u;
        __syncthreads();
        sp[tid] += v;
        __syncthreads();
    }
    unsigned int run = sp[tid] - sum;   // exclusive prefix of this thread's segment
    // pass 2: re-read counts, write exclusive prefix (in place, own segment), append actives
#pragma unroll
    for (int i = 0; i < 16; ++i) {
        uint4 v = seg[i];
        unsigned int c[4] = {v.x, v.y, v.z, v.w};
#pragma unroll
        for (int k = 0; k < 4; ++k) {
            int bin = tid * 64 + i * 4 + k;
            hb[bin] = run;
            pw[bin] = run;
            if (c[k] > 0 && run < (unsigned int)PRE_) {
                unsigned int pos = atomicAdd(&actcnt[b], 1u);
                if (pos < ACTMAX) {
                    actA[b * ACTMAX + pos] = run;
                    actB[b * ACTMAX + pos] = ((unsigned int)bin << 16) | (c[k] & 0xffffu);
                }
            }
            run += c[k];
        }
    }
}

// ---- kernel 3: scatter keys of active buckets to their bucket's slot range (arrival order)
__global__ void k_scatter(const float* __restrict__ scores,
                          const unsigned int* __restrict__ hist,   // static exclusive prefix
                          unsigned int* __restrict__ prefw,        // working prefix (atomics)
                          unsigned long long* __restrict__ skeys) {
    int idx = blockIdx.x * 256 + threadIdx.x;
    if (idx >= B_ * N_) return;
    int b;
    unsigned long long key = make_key(scores, idx, &b);
    unsigned int b16 = (unsigned int)(key >> 48);
    if (hist[b * NBIN + b16] < (unsigned int)PRE_) {
        unsigned int slot = atomicAdd(&prefw[b * NBIN + b16], 1u);
        if (slot < SKCAP) skeys[b * SKCAP + slot] = key;
    }
}

// box decode exactly in the reference op order; no FMA contraction
__device__ __forceinline__ void compute_box(int b, unsigned int n,
                                            const float* __restrict__ deltas,
                                            const float* __restrict__ im_info,
                                            float box[4]) {
#pragma clang fp contract(off)
    int a   = (int)(n % A_);
    int pos = (int)(n / A_);
    int w   = pos % W_;
    int h   = pos / W_;
    float a0 = c_anchors[a][0] + (float)(w * 16);
    float a1 = c_anchors[a][1] + (float)(h * 16);
    float a2 = c_anchors[a][2] + (float)(w * 16);
    float a3 = c_anchors[a][3] + (float)(h * 16);
    float wa  = a2 - a0 + 1.f;
    float ha  = a3 - a1 + 1.f;
    float cxa = a0 + 0.5f * wa;
    float cya = a1 + 0.5f * ha;
    int base = ((b * 4 * A_ + a * 4) * H_ + h) * W_ + w;
    const int chs = H_ * W_;
    float dx = deltas[base];
    float dy = deltas[base + chs];
    float dw = deltas[base + 2 * chs];
    float dh = deltas[base + 3 * chs];
    float pcx = dx * wa + cxa;
    float pcy = dy * ha + cya;
    float pw  = expf(dw) * wa;
    float ph  = expf(dh) * ha;
    float x1 = pcx - 0.5f * pw;
    float y1 = pcy - 0.5f * ph;
    float x2 = pcx + 0.5f * pw;
    float y2 = pcy + 0.5f * ph;
    float imh = im_info[b * 3 + 0], imw = im_info[b * 3 + 1];
    x1 = fminf(fmaxf(x1, 0.f), imw - 1.f);
    x2 = fminf(fmaxf(x2, 0.f), imw - 1.f);
    y1 = fminf(fmaxf(y1, 0.f), imh - 1.f);
    y2 = fminf(fmaxf(y2, 0.f), imh - 1.f);
    box[0] = x1; box[1] = y1; box[2] = x2; box[3] = y2;
}

// ---- kernel 4: per-bucket exact rank-by-counting + box decode into final sorted slot
__global__ __launch_bounds__(256) void k_fixup(const unsigned long long* __restrict__ skeys,
                                               const unsigned int* __restrict__ actA,
                                               const unsigned int* __restrict__ actB,
                                               const unsigned int* __restrict__ actcnt,
                                               const float* __restrict__ deltas,
                                               const float* __restrict__ im_info,
                                               float* __restrict__ sboxes) {
    int b = blockIdx.y;
    unsigned int nact = actcnt[b];
    if (nact > ACTMAX) nact = ACTMAX;
    if (blockIdx.x >= nact) return;
    int tid = threadIdx.x;
    unsigned int start = actA[b * ACTMAX + blockIdx.x];
    unsigned int ab    = actB[b * ACTMAX + blockIdx.x];
    unsigned int cnt   = ab & 0xffffu;
    unsigned int m = cnt;
    if (start + m > SKCAP) m = SKCAP - start;
    if (m > FXCAP) m = FXCAP;
    __shared__ unsigned long long lk[FXCAP];   // 16 KB
    for (unsigned int i = tid; i < m; i += 256) lk[i] = skeys[b * SKCAP + start + i];
    __syncthreads();
    float4* sb4 = (float4*)sboxes;
    for (unsigned int e = tid; e < m; e += 256) {
        unsigned long long k = lk[e];
        unsigned int r = 0;
        for (unsigned int i = 0; i < m; ++i) r += (lk[i] < k) ? 1u : 0u;
        unsigned int pos = start + r;
        if (pos < (unsigned int)PRE_) {
            unsigned int n = (unsigned int)(k & 0xffffffffull);
            float box[4];
            compute_box(b, n, deltas, im_info, box);
            sb4[b * PRE_ + pos] = make_float4(box[0], box[1], box[2], box[3]);
        }
    }
}

// ---- kernel 5: exact greedy NMS, 16 waves per image
__global__ __launch_bounds__(1024) void k_nms(const float* __restrict__ sboxes,
                                              float* __restrict__ out) {
    int b = blockIdx.x;
    int tid = threadIdx.x;
    int lane = tid & 63;
    int wave = tid >> 6;                 // 0..15
    __shared__ float4 s_box[POST_ + 64];
    __shared__ float  s_ar [POST_ + 64];
    __shared__ unsigned long long s_supw[16];
    __shared__ int s_kept;
    if (tid == 0) s_kept = 0;
    __syncthreads();

    const float4* bb = (const float4*)sboxes + b * PRE_;
    float* ob = out + b * POST_ * 5;

    for (int blk = 0; blk < PRE_; blk += 64) {
        int kept = s_kept;               // uniform (post-barrier)
        if (kept >= POST_) break;
        int idx = blk + lane;
        bool valid = idx < PRE_;
        float4 v = make_float4(0.f, 0.f, 0.f, 0.f);
        if (valid) v = bb[idx];
        float area = ((v.z - v.x) + 1.f) * ((v.w - v.y) + 1.f);
        bool sup = !valid;
        // phase a: each wave checks kept indices wave, wave+16, ...
        for (int kk = wave; kk < kept; kk += 16) {
            float4 kb = s_box[kk];
            float iw = fminf(v.z, kb.z) - fmaxf(v.x, kb.x) + 1.f;
            float ih = fminf(v.w, kb.w) - fmaxf(v.y, kb.y) + 1.f;
            iw = fmaxf(iw, 0.f); ih = fmaxf(ih, 0.f);
            float inter = iw * ih;
            float iou = inter / ((area + s_ar[kk]) - inter);
            sup = sup | (iou > 0.7f);
        }
        unsigned long long wm = __ballot(sup);
        if (lane == 0) s_supw[wave] = wm;
        __syncthreads();
        if (wave == 0) {
            unsigned long long supm = 0ull;
#pragma unroll
            for (int w2 = 0; w2 < 16; ++w2) supm |= s_supw[w2];
            // phase b: exact greedy within the 64 survivors
            unsigned long long alive = ~supm;
            unsigned long long keepm = 0ull;
            while (alive) {
                int i = __builtin_ctzll(alive);
                keepm |= (1ull << i);
                alive &= ~(1ull << i);
                float ix1 = __shfl(v.x, i), iy1 = __shfl(v.y, i);
                float ix2 = __shfl(v.z, i), iy2 = __shfl(v.w, i);
                float iar = __shfl(area, i);
                float iw = fminf(v.z, ix2) - fmaxf(v.x, ix1) + 1.f;
                float ih = fminf(v.w, iy2) - fmaxf(v.y, iy1) + 1.f;
                iw = fmaxf(iw, 0.f); ih = fmaxf(ih, 0.f);
                float inter = iw * ih;
                float iou = inter / ((area + iar) - inter);
                alive &= ~__ballot((lane > i) && (iou > 0.7f));
            }
            if ((keepm >> lane) & 1ull) {
                int my = kept + __builtin_popcountll(keepm & ((1ull << lane) - 1ull));
                s_box[my] = v;
                s_ar [my] = area;
                if (my < POST_) {
                    ob[my * 5 + 0] = (float)b;
                    ob[my * 5 + 1] = v.x; ob[my * 5 + 2] = v.y;
                    ob[my * 5 + 3] = v.z; ob[my * 5 + 4] = v.w;
                }
            }
            if (lane == 0) s_kept = kept + __builtin_popcountll(keepm);
        }
        __syncthreads();
    }
    // zero-fill rows beyond the kept count
    int kept = s_kept;
    int start = kept < POST_ ? kept : POST_;
    for (int r = start + tid; r < POST_; r += 1024) {
        ob[r * 5 + 0] = (float)b;
        ob[r * 5 + 1] = 0.f; ob[r * 5 + 2] = 0.f;
        ob[r * 5 + 3] = 0.f; ob[r * 5 + 4] = 0.f;
    }
}

extern "C" void kernel_launch(void* const* d_in, const int* in_sizes, int n_in,
                              void* d_out, int out_size, void* d_ws, size_t ws_size,
                              hipStream_t stream) {
    const float* scores  = (const float*)d_in[0];
    const float* deltas  = (const float*)d_in[1];
    const float* im_info = (const float*)d_in[2];
    float* out = (float*)d_out;

    // workspace layout (16-aligned blocks)
    char* ws = (char*)d_ws;
    unsigned int*       hist   = (unsigned int*)      (ws);             // 1,048,576
    unsigned int*       prefw  = (unsigned int*)      (ws + 1048576);   // 1,048,576
    unsigned long long* skeys  = (unsigned long long*)(ws + 2097152);   //   262,144
    unsigned int*       actA   = (unsigned int*)      (ws + 2359296);   //     4,096
    unsigned int*       actB   = (unsigned int*)      (ws + 2363392);   //     4,096
    unsigned int*       actcnt = (unsigned int*)      (ws + 2367488);   //        32
    float*              sbx    = (float*)             (ws + 2367520);   //   384,000

    hipMemsetAsync(hist, 0, B_ * NBIN * sizeof(unsigned int), stream);
    hipMemsetAsync(actcnt, 0, B_ * sizeof(unsigned int), stream);

    const int total = B_ * N_;
    k_hist<<<(total + 255) / 256, 256, 0, stream>>>(scores, hist);
    k_prefix<<<B_, 1024, 0, stream>>>(hist, prefw, actA, actB, actcnt);
    k_scatter<<<(total + 255) / 256, 256, 0, stream>>>(scores, hist, prefw, skeys);
    dim3 fgrid(ACTMAX, B_);
    k_fixup<<<fgrid, 256, 0, stream>>>(skeys, actA, actB, actcnt, deltas, im_info, sbx);
    k_nms<<<B_, 1024, 0, stream>>>(sbx, out);
}

// Round 6
// 136.324 us; speedup vs baseline: 5.9259x; 1.7257x over previous
//
#include <hip/hip_runtime.h>
#include <stdint.h>

#define B_     4
#define A_     9
#define H_     50
#define W_     76
#define N_     (H_ * W_ * A_)   // 34200
#define PRE_   6000
#define POST_  300
#define NBIN   65536
#define NSEG   256
#define SKCAP  8192
#define ACTMAX 256
#define FXCAP  2048

// generate_anchors(16) precomputed (exact, verified against the numpy code)
__constant__ float c_anchors[9][4] = {
    { -84.f,  -40.f,  99.f,  55.f},
    {-176.f,  -88.f, 191.f, 103.f},
    {-360.f, -184.f, 375.f, 199.f},
    { -56.f,  -56.f,  71.f,  71.f},
    {-120.f, -120.f, 135.f, 135.f},
    {-248.f, -248.f, 263.f, 263.f},
    { -36.f,  -80.f,  51.f,  95.f},
    { -80.f, -168.f,  95.f, 183.f},
    {-168.f, -344.f, 183.f, 359.f},
};

// composite key: (~score_bits)<<32 | n  — ascending key == descending score, ascending idx
__device__ __forceinline__ unsigned long long make_key(const float* __restrict__ scores,
                                                       int idx, int* pb) {
    int w = idx % W_;
    int h = (idx / W_) % H_;
    int a = (idx / (W_ * H_)) % A_;
    int b = idx / (W_ * H_ * A_);
    float s = scores[(((b * 2 * A_) + A_ + a) * H_ + h) * W_ + w];
    unsigned int sb = __float_as_uint(s);          // s >= 0 -> monotone bits
    unsigned int n  = (unsigned int)((h * W_ + w) * A_ + a);
    *pb = b;
    return (((unsigned long long)(~sb)) << 32) | (unsigned long long)n;
}

// ---- kernel 1: 16-bit-prefix histogram of keys
__global__ void k_hist(const float* __restrict__ scores,
                       unsigned int* __restrict__ hist) {
    int idx = blockIdx.x * 256 + threadIdx.x;
    if (idx >= B_ * N_) return;
    int b;
    unsigned long long key = make_key(scores, idx, &b);
    atomicAdd(&hist[b * NBIN + (unsigned int)(key >> 48)], 1u);
}

// ---- kernel 2a: per-segment sums (coalesced), 256 bins per block
__global__ __launch_bounds__(256) void k_prefix1(const unsigned int* __restrict__ hist,
                                                 unsigned int* __restrict__ segsum) {
    int b = blockIdx.y, seg = blockIdx.x, tid = threadIdx.x;
    int lane = tid & 63, wid = tid >> 6;
    unsigned int v = hist[b * NBIN + seg * 256 + tid];
#pragma unroll
    for (int off = 32; off > 0; off >>= 1) v += __shfl_down(v, off);
    __shared__ unsigned int wsum[4];
    if (lane == 0) wsum[wid] = v;
    __syncthreads();
    if (tid == 0) segsum[b * NSEG + seg] = wsum[0] + wsum[1] + wsum[2] + wsum[3];
}

// ---- kernel 2b: exclusive scan of the 256 segment sums (1 block/image)
__global__ __launch_bounds__(256) void k_prefix2(const unsigned int* __restrict__ segsum,
                                                 unsigned int* __restrict__ segbase) {
    int b = blockIdx.x, tid = threadIdx.x;
    __shared__ unsigned int sp[256];
    unsigned int own = segsum[b * NSEG + tid];
    sp[tid] = own;
    __syncthreads();
    for (int off = 1; off < 256; off <<= 1) {
        unsigned int v = (tid >= off) ? sp[tid - off] : 0u;
        __syncthreads();
        sp[tid] += v;
        __syncthreads();
    }
    segbase[b * NSEG + tid] = sp[tid] - own;   // exclusive
}

// ---- kernel 2c: intra-segment exclusive scan + segbase; coalesced prefix writes;
//      append active buckets (cnt>0 && start<PRE_)
__global__ __launch_bounds__(256) void k_prefix3(unsigned int* __restrict__ hist,
                                                 const unsigned int* __restrict__ segbase,
                                                 unsigned int* __restrict__ prefw,
                                                 unsigned int* __restrict__ actA,
                                                 unsigned int* __restrict__ actB,
                                                 unsigned int* __restrict__ actcnt) {
    int b = blockIdx.y, seg = blockIdx.x, tid = threadIdx.x;
    int bin = seg * 256 + tid;
    unsigned int c = hist[b * NBIN + bin];
    __shared__ unsigned int sp[256];
    sp[tid] = c;
    __syncthreads();
    for (int off = 1; off < 256; off <<= 1) {
        unsigned int v = (tid >= off) ? sp[tid - off] : 0u;
        __syncthreads();
        sp[tid] += v;
        __syncthreads();
    }
    unsigned int run = segbase[b * NSEG + seg] + sp[tid] - c;   // global exclusive prefix
    hist[b * NBIN + bin]  = run;    // static prefix (coalesced)
    prefw[b * NBIN + bin] = run;    // working prefix (coalesced)
    if (c > 0 && run < (unsigned int)PRE_) {
        unsigned int pos = atomicAdd(&actcnt[b], 1u);
        if (pos < ACTMAX) {
            actA[b * ACTMAX + pos] = run;
            actB[b * ACTMAX + pos] = ((unsigned int)bin << 16) | (c & 0xffffu);
        }
    }
}

// ---- kernel 3: scatter keys of active buckets to their bucket's slot range (arrival order)
__global__ void k_scatter(const float* __restrict__ scores,
                          const unsigned int* __restrict__ hist,   // static exclusive prefix
                          unsigned int* __restrict__ prefw,        // working prefix (atomics)
                          unsigned long long* __restrict__ skeys) {
    int idx = blockIdx.x * 256 + threadIdx.x;
    if (idx >= B_ * N_) return;
    int b;
    unsigned long long key = make_key(scores, idx, &b);
    unsigned int b16 = (unsigned int)(key >> 48);
    if (hist[b * NBIN + b16] < (unsigned int)PRE_) {
        unsigned int slot = atomicAdd(&prefw[b * NBIN + b16], 1u);
        if (slot < SKCAP) skeys[b * SKCAP + slot] = key;
    }
}

// box decode exactly in the reference op order; no FMA contraction
__device__ __forceinline__ void compute_box(int b, unsigned int n,
                                            const float* __restrict__ deltas,
                                            const float* __restrict__ im_info,
                                            float box[4]) {
#pragma clang fp contract(off)
    int a   = (int)(n % A_);
    int pos = (int)(n / A_);
    int w   = pos % W_;
    int h   = pos / W_;
    float a0 = c_anchors[a][0] + (float)(w * 16);
    float a1 = c_anchors[a][1] + (float)(h * 16);
    float a2 = c_anchors[a][2] + (float)(w * 16);
    float a3 = c_anchors[a][3] + (float)(h * 16);
    float wa  = a2 - a0 + 1.f;
    float ha  = a3 - a1 + 1.f;
    float cxa = a0 + 0.5f * wa;
    float cya = a1 + 0.5f * ha;
    int base = ((b * 4 * A_ + a * 4) * H_ + h) * W_ + w;
    const int chs = H_ * W_;
    float dx = deltas[base];
    float dy = deltas[base + chs];
    float dw = deltas[base + 2 * chs];
    float dh = deltas[base + 3 * chs];
    float pcx = dx * wa + cxa;
    float pcy = dy * ha + cya;
    float pw  = expf(dw) * wa;
    float ph  = expf(dh) * ha;
    float x1 = pcx - 0.5f * pw;
    float y1 = pcy - 0.5f * ph;
    float x2 = pcx + 0.5f * pw;
    float y2 = pcy + 0.5f * ph;
    float imh = im_info[b * 3 + 0], imw = im_info[b * 3 + 1];
    x1 = fminf(fmaxf(x1, 0.f), imw - 1.f);
    x2 = fminf(fmaxf(x2, 0.f), imw - 1.f);
    y1 = fminf(fmaxf(y1, 0.f), imh - 1.f);
    y2 = fminf(fmaxf(y2, 0.f), imh - 1.f);
    box[0] = x1; box[1] = y1; box[2] = x2; box[3] = y2;
}

// ---- kernel 4: per-bucket exact rank-by-counting + box decode into final sorted slot
__global__ __launch_bounds__(256) void k_fixup(const unsigned long long* __restrict__ skeys,
                                               const unsigned int* __restrict__ actA,
                                               const unsigned int* __restrict__ actB,
                                               const unsigned int* __restrict__ actcnt,
                                               const float* __restrict__ deltas,
                                               const float* __restrict__ im_info,
                                               float* __restrict__ sboxes) {
    int b = blockIdx.y;
    unsigned int nact = actcnt[b];
    if (nact > ACTMAX) nact = ACTMAX;
    if (blockIdx.x >= nact) return;
    int tid = threadIdx.x;
    unsigned int start = actA[b * ACTMAX + blockIdx.x];
    unsigned int ab    = actB[b * ACTMAX + blockIdx.x];
    unsigned int cnt   = ab & 0xffffu;
    unsigned int m = cnt;
    if (start + m > SKCAP) m = SKCAP - start;
    if (m > FXCAP) m = FXCAP;
    __shared__ unsigned long long lk[FXCAP];   // 16 KB
    for (unsigned int i = tid; i < m; i += 256) lk[i] = skeys[b * SKCAP + start + i];
    __syncthreads();
    float4* sb4 = (float4*)sboxes;
    for (unsigned int e = tid; e < m; e += 256) {
        unsigned long long k = lk[e];
        unsigned int r = 0;
        for (unsigned int i = 0; i < m; ++i) r += (lk[i] < k) ? 1u : 0u;
        unsigned int pos = start + r;
        if (pos < (unsigned int)PRE_) {
            unsigned int n = (unsigned int)(k & 0xffffffffull);
            float box[4];
            compute_box(b, n, deltas, im_info, box);
            sb4[b * PRE_ + pos] = make_float4(box[0], box[1], box[2], box[3]);
        }
    }
}

// ---- kernel 5: exact greedy NMS, 16 waves per image
__global__ __launch_bounds__(1024) void k_nms(const float* __restrict__ sboxes,
                                              float* __restrict__ out) {
    int b = blockIdx.x;
    int tid = threadIdx.x;
    int lane = tid & 63;
    int wave = tid >> 6;                 // 0..15
    __shared__ float4 s_box[POST_ + 64];
    __shared__ float  s_ar [POST_ + 64];
    __shared__ unsigned long long s_supw[16];
    __shared__ int s_kept;
    if (tid == 0) s_kept = 0;
    __syncthreads();

    const float4* bb = (const float4*)sboxes + b * PRE_;
    float* ob = out + b * POST_ * 5;

    for (int blk = 0; blk < PRE_; blk += 64) {
        int kept = s_kept;               // uniform (post-barrier)
        if (kept >= POST_) break;
        int idx = blk + lane;
        bool valid = idx < PRE_;
        float4 v = make_float4(0.f, 0.f, 0.f, 0.f);
        if (valid) v = bb[idx];
        float area = ((v.z - v.x) + 1.f) * ((v.w - v.y) + 1.f);
        bool sup = !valid;
        // phase a: each wave checks kept indices wave, wave+16, ...
        for (int kk = wave; kk < kept; kk += 16) {
            float4 kb = s_box[kk];
            float iw = fminf(v.z, kb.z) - fmaxf(v.x, kb.x) + 1.f;
            float ih = fminf(v.w, kb.w) - fmaxf(v.y, kb.y) + 1.f;
            iw = fmaxf(iw, 0.f); ih = fmaxf(ih, 0.f);
            float inter = iw * ih;
            float iou = inter / ((area + s_ar[kk]) - inter);
            sup = sup | (iou > 0.7f);
        }
        unsigned long long wm = __ballot(sup);
        if (lane == 0) s_supw[wave] = wm;
        __syncthreads();
        if (wave == 0) {
            unsigned long long supm = 0ull;
#pragma unroll
            for (int w2 = 0; w2 < 16; ++w2) supm |= s_supw[w2];
            // phase b: exact greedy within the 64 survivors
            unsigned long long alive = ~supm;
            unsigned long long keepm = 0ull;
            while (alive) {
                int i = __builtin_ctzll(alive);
                keepm |= (1ull << i);
                alive &= ~(1ull << i);
                float ix1 = __shfl(v.x, i), iy1 = __shfl(v.y, i);
                float ix2 = __shfl(v.z, i), iy2 = __shfl(v.w, i);
                float iar = __shfl(area, i);
                float iw = fminf(v.z, ix2) - fmaxf(v.x, ix1) + 1.f;
                float ih = fminf(v.w, iy2) - fmaxf(v.y, iy1) + 1.f;
                iw = fmaxf(iw, 0.f); ih = fmaxf(ih, 0.f);
                float inter = iw * ih;
                float iou = inter / ((area + iar) - inter);
                alive &= ~__ballot((lane > i) && (iou > 0.7f));
            }
            if ((keepm >> lane) & 1ull) {
                int my = kept + __builtin_popcountll(keepm & ((1ull << lane) - 1ull));
                s_box[my] = v;
                s_ar [my] = area;
                if (my < POST_) {
                    ob[my * 5 + 0] = (float)b;
                    ob[my * 5 + 1] = v.x; ob[my * 5 + 2] = v.y;
                    ob[my * 5 + 3] = v.z; ob[my * 5 + 4] = v.w;
                }
            }
            if (lane == 0) s_kept = kept + __builtin_popcountll(keepm);
        }
        __syncthreads();
    }
    // zero-fill rows beyond the kept count
    int kept = s_kept;
    int start = kept < POST_ ? kept : POST_;
    for (int r = start + tid; r < POST_; r += 1024) {
        ob[r * 5 + 0] = (float)b;
        ob[r * 5 + 1] = 0.f; ob[r * 5 + 2] = 0.f;
        ob[r * 5 + 3] = 0.f; ob[r * 5 + 4] = 0.f;
    }
}

extern "C" void kernel_launch(void* const* d_in, const int* in_sizes, int n_in,
                              void* d_out, int out_size, void* d_ws, size_t ws_size,
                              hipStream_t stream) {
    const float* scores  = (const float*)d_in[0];
    const float* deltas  = (const float*)d_in[1];
    const float* im_info = (const float*)d_in[2];
    float* out = (float*)d_out;

    // workspace layout (16-aligned blocks)
    char* ws = (char*)d_ws;
    unsigned int*       hist    = (unsigned int*)      (ws);             // 1,048,576
    unsigned int*       prefw   = (unsigned int*)      (ws + 1048576);   // 1,048,576
    unsigned long long* skeys   = (unsigned long long*)(ws + 2097152);   //   262,144
    unsigned int*       segsum  = (unsigned int*)      (ws + 2359296);   //     4,096
    unsigned int*       segbase = (unsigned int*)      (ws + 2363392);   //     4,096
    unsigned int*       actA    = (unsigned int*)      (ws + 2367488);   //     4,096
    unsigned int*       actB    = (unsigned int*)      (ws + 2371584);   //     4,096
    unsigned int*       actcnt  = (unsigned int*)      (ws + 2375680);   //        32
    float*              sbx     = (float*)             (ws + 2375712);   //   384,000

    hipMemsetAsync(hist, 0, B_ * NBIN * sizeof(unsigned int), stream);
    hipMemsetAsync(actcnt, 0, B_ * sizeof(unsigned int), stream);

    const int total = B_ * N_;
    dim3 sgrid(NSEG, B_);
    k_hist<<<(total + 255) / 256, 256, 0, stream>>>(scores, hist);
    k_prefix1<<<sgrid, 256, 0, stream>>>(hist, segsum);
    k_prefix2<<<B_, 256, 0, stream>>>(segsum, segbase);
    k_prefix3<<<sgrid, 256, 0, stream>>>(hist, segbase, prefw, actA, actB, actcnt);
    k_scatter<<<(total + 255) / 256, 256, 0, stream>>>(scores, hist, prefw, skeys);
    dim3 fgrid(ACTMAX, B_);
    k_fixup<<<fgrid, 256, 0, stream>>>(skeys, actA, actB, actcnt, deltas, im_info, sbx);
    k_nms<<<B_, 1024, 0, stream>>>(sbx, out);
}

// Round 7
// 126.464 us; speedup vs baseline: 6.3880x; 1.0780x over previous
//
#include <hip/hip_runtime.h>
#include <stdint.h>

#define B_     4
#define A_     9
#define H_     50
#define W_     76
#define N_     (H_ * W_ * A_)   // 34200
#define PRE_   6000
#define POST_  300
#define NBIN   65536
#define NSEG   256
#define SKCAP  8192
#define ACTMAX 256
#define FXCAP  2048
#define NB_    94               // ceil(PRE_/64)

// generate_anchors(16) precomputed (exact, verified against the numpy code)
__constant__ float c_anchors[9][4] = {
    { -84.f,  -40.f,  99.f,  55.f},
    {-176.f,  -88.f, 191.f, 103.f},
    {-360.f, -184.f, 375.f, 199.f},
    { -56.f,  -56.f,  71.f,  71.f},
    {-120.f, -120.f, 135.f, 135.f},
    {-248.f, -248.f, 263.f, 263.f},
    { -36.f,  -80.f,  51.f,  95.f},
    { -80.f, -168.f,  95.f, 183.f},
    {-168.f, -344.f, 183.f, 359.f},
};

// composite key: (~score_bits)<<32 | n  — ascending key == descending score, ascending idx
__device__ __forceinline__ unsigned long long make_key(const float* __restrict__ scores,
                                                       int idx, int* pb) {
    int w = idx % W_;
    int h = (idx / W_) % H_;
    int a = (idx / (W_ * H_)) % A_;
    int b = idx / (W_ * H_ * A_);
    float s = scores[(((b * 2 * A_) + A_ + a) * H_ + h) * W_ + w];
    unsigned int sb = __float_as_uint(s);          // s >= 0 -> monotone bits
    unsigned int n  = (unsigned int)((h * W_ + w) * A_ + a);
    *pb = b;
    return (((unsigned long long)(~sb)) << 32) | (unsigned long long)n;
}

// ---- kernel 1: 16-bit-prefix histogram of keys
__global__ void k_hist(const float* __restrict__ scores,
                       unsigned int* __restrict__ hist) {
    int idx = blockIdx.x * 256 + threadIdx.x;
    if (idx >= B_ * N_) return;
    int b;
    unsigned long long key = make_key(scores, idx, &b);
    atomicAdd(&hist[b * NBIN + (unsigned int)(key >> 48)], 1u);
}

// ---- kernel 2a: per-segment sums (coalesced), 256 bins per block
__global__ __launch_bounds__(256) void k_prefix1(const unsigned int* __restrict__ hist,
                                                 unsigned int* __restrict__ segsum) {
    int b = blockIdx.y, seg = blockIdx.x, tid = threadIdx.x;
    int lane = tid & 63, wid = tid >> 6;
    unsigned int v = hist[b * NBIN + seg * 256 + tid];
#pragma unroll
    for (int off = 32; off > 0; off >>= 1) v += __shfl_down(v, off);
    __shared__ unsigned int wsum[4];
    if (lane == 0) wsum[wid] = v;
    __syncthreads();
    if (tid == 0) segsum[b * NSEG + seg] = wsum[0] + wsum[1] + wsum[2] + wsum[3];
}

// ---- kernel 2b: exclusive scan of the 256 segment sums (1 block/image)
__global__ __launch_bounds__(256) void k_prefix2(const unsigned int* __restrict__ segsum,
                                                 unsigned int* __restrict__ segbase) {
    int b = blockIdx.x, tid = threadIdx.x;
    __shared__ unsigned int sp[256];
    unsigned int own = segsum[b * NSEG + tid];
    sp[tid] = own;
    __syncthreads();
    for (int off = 1; off < 256; off <<= 1) {
        unsigned int v = (tid >= off) ? sp[tid - off] : 0u;
        __syncthreads();
        sp[tid] += v;
        __syncthreads();
    }
    segbase[b * NSEG + tid] = sp[tid] - own;   // exclusive
}

// ---- kernel 2c: intra-segment exclusive scan + segbase; coalesced prefix writes;
//      append active buckets (cnt>0 && start<PRE_)
__global__ __launch_bounds__(256) void k_prefix3(unsigned int* __restrict__ hist,
                                                 const unsigned int* __restrict__ segbase,
                                                 unsigned int* __restrict__ prefw,
                                                 unsigned int* __restrict__ actA,
                                                 unsigned int* __restrict__ actB,
                                                 unsigned int* __restrict__ actcnt) {
    int b = blockIdx.y, seg = blockIdx.x, tid = threadIdx.x;
    int bin = seg * 256 + tid;
    unsigned int c = hist[b * NBIN + bin];
    __shared__ unsigned int sp[256];
    sp[tid] = c;
    __syncthreads();
    for (int off = 1; off < 256; off <<= 1) {
        unsigned int v = (tid >= off) ? sp[tid - off] : 0u;
        __syncthreads();
        sp[tid] += v;
        __syncthreads();
    }
    unsigned int run = segbase[b * NSEG + seg] + sp[tid] - c;   // global exclusive prefix
    hist[b * NBIN + bin]  = run;    // static prefix (coalesced)
    prefw[b * NBIN + bin] = run;    // working prefix (coalesced)
    if (c > 0 && run < (unsigned int)PRE_) {
        unsigned int pos = atomicAdd(&actcnt[b], 1u);
        if (pos < ACTMAX) {
            actA[b * ACTMAX + pos] = run;
            actB[b * ACTMAX + pos] = ((unsigned int)bin << 16) | (c & 0xffffu);
        }
    }
}

// ---- kernel 3: scatter keys of active buckets to their bucket's slot range (arrival order)
__global__ void k_scatter(const float* __restrict__ scores,
                          const unsigned int* __restrict__ hist,   // static exclusive prefix
                          unsigned int* __restrict__ prefw,        // working prefix (atomics)
                          unsigned long long* __restrict__ skeys) {
    int idx = blockIdx.x * 256 + threadIdx.x;
    if (idx >= B_ * N_) return;
    int b;
    unsigned long long key = make_key(scores, idx, &b);
    unsigned int b16 = (unsigned int)(key >> 48);
    if (hist[b * NBIN + b16] < (unsigned int)PRE_) {
        unsigned int slot = atomicAdd(&prefw[b * NBIN + b16], 1u);
        if (slot < SKCAP) skeys[b * SKCAP + slot] = key;
    }
}

// box decode exactly in the reference op order; no FMA contraction
__device__ __forceinline__ void compute_box(int b, unsigned int n,
                                            const float* __restrict__ deltas,
                                            const float* __restrict__ im_info,
                                            float box[4]) {
#pragma clang fp contract(off)
    int a   = (int)(n % A_);
    int pos = (int)(n / A_);
    int w   = pos % W_;
    int h   = pos / W_;
    float a0 = c_anchors[a][0] + (float)(w * 16);
    float a1 = c_anchors[a][1] + (float)(h * 16);
    float a2 = c_anchors[a][2] + (float)(w * 16);
    float a3 = c_anchors[a][3] + (float)(h * 16);
    float wa  = a2 - a0 + 1.f;
    float ha  = a3 - a1 + 1.f;
    float cxa = a0 + 0.5f * wa;
    float cya = a1 + 0.5f * ha;
    int base = ((b * 4 * A_ + a * 4) * H_ + h) * W_ + w;
    const int chs = H_ * W_;
    float dx = deltas[base];
    float dy = deltas[base + chs];
    float dw = deltas[base + 2 * chs];
    float dh = deltas[base + 3 * chs];
    float pcx = dx * wa + cxa;
    float pcy = dy * ha + cya;
    float pw  = expf(dw) * wa;
    float ph  = expf(dh) * ha;
    float x1 = pcx - 0.5f * pw;
    float y1 = pcy - 0.5f * ph;
    float x2 = pcx + 0.5f * pw;
    float y2 = pcy + 0.5f * ph;
    float imh = im_info[b * 3 + 0], imw = im_info[b * 3 + 1];
    x1 = fminf(fmaxf(x1, 0.f), imw - 1.f);
    x2 = fminf(fmaxf(x2, 0.f), imw - 1.f);
    y1 = fminf(fmaxf(y1, 0.f), imh - 1.f);
    y2 = fminf(fmaxf(y2, 0.f), imh - 1.f);
    box[0] = x1; box[1] = y1; box[2] = x2; box[3] = y2;
}

// ---- kernel 4: per-bucket exact rank-by-counting + box decode into final sorted slot
__global__ __launch_bounds__(256) void k_fixup(const unsigned long long* __restrict__ skeys,
                                               const unsigned int* __restrict__ actA,
                                               const unsigned int* __restrict__ actB,
                                               const unsigned int* __restrict__ actcnt,
                                               const float* __restrict__ deltas,
                                               const float* __restrict__ im_info,
                                               float* __restrict__ sboxes) {
    int b = blockIdx.y;
    unsigned int nact = actcnt[b];
    if (nact > ACTMAX) nact = ACTMAX;
    if (blockIdx.x >= nact) return;
    int tid = threadIdx.x;
    unsigned int start = actA[b * ACTMAX + blockIdx.x];
    unsigned int ab    = actB[b * ACTMAX + blockIdx.x];
    unsigned int cnt   = ab & 0xffffu;
    unsigned int m = cnt;
    if (start + m > SKCAP) m = SKCAP - start;
    if (m > FXCAP) m = FXCAP;
    __shared__ unsigned long long lk[FXCAP];   // 16 KB
    for (unsigned int i = tid; i < m; i += 256) lk[i] = skeys[b * SKCAP + start + i];
    __syncthreads();
    float4* sb4 = (float4*)sboxes;
    for (unsigned int e = tid; e < m; e += 256) {
        unsigned long long k = lk[e];
        unsigned int r = 0;
        for (unsigned int i = 0; i < m; ++i) r += (lk[i] < k) ? 1u : 0u;
        unsigned int pos = start + r;
        if (pos < (unsigned int)PRE_) {
            unsigned int n = (unsigned int)(k & 0xffffffffull);
            float box[4];
            compute_box(b, n, deltas, im_info, box);
            sb4[b * PRE_ + pos] = make_float4(box[0], box[1], box[2], box[3]);
        }
    }
}

// ---- kernel 5: per-block 64x64 intra-block suppression masks (fully parallel)
//      mask row i, bit j = (j > i) && IoU(i,j) > 0.7   (identical float expr to NMS)
__global__ __launch_bounds__(64) void k_mask(const float* __restrict__ sboxes,
                                             unsigned long long* __restrict__ mask) {
    int b = blockIdx.y, blk = blockIdx.x;
    int lane = threadIdx.x;
    const float4* bb = (const float4*)sboxes + b * PRE_;
    int idx = blk * 64 + lane;
    float4 v = bb[idx < PRE_ ? idx : PRE_ - 1];
    float area = ((v.z - v.x) + 1.f) * ((v.w - v.y) + 1.f);
    unsigned long long myrow = 0ull;
    for (int i = 0; i < 64; ++i) {
        float ix1 = __shfl(v.x, i), iy1 = __shfl(v.y, i);
        float ix2 = __shfl(v.z, i), iy2 = __shfl(v.w, i);
        float iar = __shfl(area, i);
        float iw = fminf(v.z, ix2) - fmaxf(v.x, ix1) + 1.f;
        float ih = fminf(v.w, iy2) - fmaxf(v.y, iy1) + 1.f;
        iw = fmaxf(iw, 0.f); ih = fmaxf(ih, 0.f);
        float inter = iw * ih;
        float iou = inter / ((area + iar) - inter);
        unsigned long long bal = __ballot((lane > i) && (iou > 0.7f));
        if (lane == i) myrow = bal;
    }
    mask[(b * NB_ + blk) * 64 + lane] = myrow;
}

// ---- kernel 6: exact greedy NMS, pipelined:
//      wave 0 resolves block k (delta-check vs block k-1's new keeps + mask resolve),
//      waves 1-15 concurrently run the long kept-list check for block k+1.
//      One barrier per iteration; parity-double-buffered LDS hand-off slots.
__global__ __launch_bounds__(1024) void k_nms(const float* __restrict__ sboxes,
                                              const unsigned long long* __restrict__ mask,
                                              float* __restrict__ out) {
    int b = blockIdx.x;
    int tid = threadIdx.x;
    int lane = tid & 63;
    int wave = tid >> 6;                     // 0..15
    __shared__ float4 s_box[POST_ + 64];
    __shared__ float  s_ar [POST_ + 64];
    __shared__ unsigned long long s_pend[2][16];
    __shared__ int s_cnt[2];
    __shared__ int s_final;
    if (tid < 32) ((unsigned long long*)s_pend)[tid] = 0ull;
    if (tid < 2) s_cnt[tid] = 0;
    if (tid == 0) s_final = 0;
    __syncthreads();

    const float4* bb = (const float4*)sboxes + b * PRE_;
    float* ob = out + b * POST_ * 5;

    // register prefetch: wave0 holds block 0 (+mask row); waves 1-15 hold block 1
    float4 vme;
    unsigned long long rowme = 0ull;
    if (wave == 0) {
        vme = bb[lane];                       // block 0 (64 <= PRE_, all valid)
        rowme = mask[(b * NB_ + 0) * 64 + lane];
    } else {
        vme = bb[64 + lane];                  // block 1
    }

    for (int k = 0; k < NB_; ++k) {
        int Cm1 = s_cnt[(k + 1) & 1];         // kept count through block k-1
        if (Cm1 >= POST_) break;
        if (wave == 0) {
            int idx = k * 64 + lane;
            bool valid = idx < PRE_;
            float4 v = vme;
            unsigned long long row = rowme;
            if (k + 1 < NB_) {                 // prefetch block k+1
                int nidx = (k + 1) * 64 + lane;
                vme = bb[nidx < PRE_ ? nidx : PRE_ - 1];
                rowme = mask[(b * NB_ + k + 1) * 64 + lane];
            }
            float area = ((v.z - v.x) + 1.f) * ((v.w - v.y) + 1.f);
            int Cm2 = s_cnt[k & 1];           // kept count through block k-2
            bool sup = !valid;
            for (int kk = Cm2; kk < Cm1; ++kk) {   // delta: keeps added by block k-1
                float4 kb = s_box[kk];
                float iw = fminf(v.z, kb.z) - fmaxf(v.x, kb.x) + 1.f;
                float ih = fminf(v.w, kb.w) - fmaxf(v.y, kb.y) + 1.f;
                iw = fmaxf(iw, 0.f); ih = fmaxf(ih, 0.f);
                float inter = iw * ih;
                float iou = inter / ((area + s_ar[kk]) - inter);
                sup = sup | (iou > 0.7f);
            }
            unsigned long long supm = __ballot(sup);
            const unsigned long long* pnd = s_pend[k & 1];
#pragma unroll
            for (int w2 = 1; w2 < 16; ++w2) supm |= pnd[w2];
            unsigned int rlo = (unsigned int)row;
            unsigned int rhi = (unsigned int)(row >> 32);
            unsigned long long alive = ~supm;
            unsigned long long keepm = 0ull;
            while (alive) {
                int i = __builtin_ctzll(alive);     // uniform across wave 0
                keepm |= (1ull << i);
                alive &= ~(1ull << i);
                unsigned long long mlo = (unsigned int)__builtin_amdgcn_readlane((int)rlo, i);
                unsigned long long mhi = (unsigned int)__builtin_amdgcn_readlane((int)rhi, i);
                alive &= ~((mhi << 32) | mlo);
            }
            if ((keepm >> lane) & 1ull) {
                int my = Cm1 + __builtin_popcountll(keepm & ((1ull << lane) - 1ull));
                s_box[my] = v;
                s_ar [my] = area;
                if (my < POST_) {
                    ob[my * 5 + 0] = (float)b;
                    ob[my * 5 + 1] = v.x; ob[my * 5 + 2] = v.y;
                    ob[my * 5 + 3] = v.z; ob[my * 5 + 4] = v.w;
                }
            }
            if (lane == 0) {
                int nc = Cm1 + __builtin_popcountll(keepm);
                s_cnt[k & 1] = nc;
                s_final = nc;
            }
        } else if (k + 1 < NB_) {
            // phase-a for block k+1 vs kept[0..Cm1) (gap covered by wave0's delta next iter)
            int jdx = (k + 1) * 64 + lane;
            bool valid2 = jdx < PRE_;
            float4 v2 = vme;
            if (k + 2 < NB_) {                 // prefetch block k+2
                int nj = (k + 2) * 64 + lane;
                vme = bb[nj < PRE_ ? nj : PRE_ - 1];
            }
            float area2 = ((v2.z - v2.x) + 1.f) * ((v2.w - v2.y) + 1.f);
            bool sup2 = !valid2;
            for (int kk = wave - 1; kk < Cm1; kk += 15) {
                float4 kb = s_box[kk];
                float iw = fminf(v2.z, kb.z) - fmaxf(v2.x, kb.x) + 1.f;
                float ih = fminf(v2.w, kb.w) - fmaxf(v2.y, kb.y) + 1.f;
                iw = fmaxf(iw, 0.f); ih = fmaxf(ih, 0.f);
                float inter = iw * ih;
                float iou = inter / ((area2 + s_ar[kk]) - inter);
                sup2 = sup2 | (iou > 0.7f);
            }
            unsigned long long bal = __ballot(sup2);
            if (lane == 0) s_pend[(k + 1) & 1][wave] = bal;
        }
        __syncthreads();
    }
    __syncthreads();
    int kept = s_final;
    int start = kept < POST_ ? kept : POST_;
    for (int r = start + tid; r < POST_; r += 1024) {
        ob[r * 5 + 0] = (float)b;
        ob[r * 5 + 1] = 0.f; ob[r * 5 + 2] = 0.f;
        ob[r * 5 + 3] = 0.f; ob[r * 5 + 4] = 0.f;
    }
}

extern "C" void kernel_launch(void* const* d_in, const int* in_sizes, int n_in,
                              void* d_out, int out_size, void* d_ws, size_t ws_size,
                              hipStream_t stream) {
    const float* scores  = (const float*)d_in[0];
    const float* deltas  = (const float*)d_in[1];
    const float* im_info = (const float*)d_in[2];
    float* out = (float*)d_out;

    // workspace layout (16-aligned blocks)
    char* ws = (char*)d_ws;
    unsigned int*       hist    = (unsigned int*)      (ws);             // 1,048,576
    unsigned int*       prefw   = (unsigned int*)      (ws + 1048576);   // 1,048,576
    unsigned long long* skeys   = (unsigned long long*)(ws + 2097152);   //   262,144
    unsigned int*       segsum  = (unsigned int*)      (ws + 2359296);   //     4,096
    unsigned int*       segbase = (unsigned int*)      (ws + 2363392);   //     4,096
    unsigned int*       actA    = (unsigned int*)      (ws + 2367488);   //     4,096
    unsigned int*       actB    = (unsigned int*)      (ws + 2371584);   //     4,096
    unsigned int*       actcnt  = (unsigned int*)      (ws + 2375680);   //        32
    float*              sbx     = (float*)             (ws + 2375712);   //   384,000
    unsigned long long* maskb   = (unsigned long long*)(ws + 2759712);   //   192,512

    hipMemsetAsync(hist, 0, B_ * NBIN * sizeof(unsigned int), stream);
    hipMemsetAsync(actcnt, 0, B_ * sizeof(unsigned int), stream);

    const int total = B_ * N_;
    dim3 sgrid(NSEG, B_);
    k_hist<<<(total + 255) / 256, 256, 0, stream>>>(scores, hist);
    k_prefix1<<<sgrid, 256, 0, stream>>>(hist, segsum);
    k_prefix2<<<B_, 256, 0, stream>>>(segsum, segbase);
    k_prefix3<<<sgrid, 256, 0, stream>>>(hist, segbase, prefw, actA, actB, actcnt);
    k_scatter<<<(total + 255) / 256, 256, 0, stream>>>(scores, hist, prefw, skeys);
    dim3 fgrid(ACTMAX, B_);
    k_fixup<<<fgrid, 256, 0, stream>>>(skeys, actA, actB, actcnt, deltas, im_info, sbx);
    dim3 mgrid(NB_, B_);
    k_mask<<<mgrid, 64, 0, stream>>>(sbx, maskb);
    k_nms<<<B_, 1024, 0, stream>>>(sbx, maskb, out);
}